// Round 1
// baseline (44051.556 us; speedup 1.0000x reference)
//
#include <hip/hip_runtime.h>

#define B_ 1024
#define T_ 1024
#define I_ 18
#define H_ 256

typedef _Float16 f16;
typedef _Float16 f16x8 __attribute__((ext_vector_type(8)));
typedef float f32x4 __attribute__((ext_vector_type(4)));

#define MFMA16(a, b, c) __builtin_amdgcn_mfma_f32_16x16x32_f16((a), (b), (c), 0, 0, 0)

#define NFRAG_BIG (3 * 48 * 8)        // 3 weight matrices, 48 n-tiles, 8 k-tiles
#define WSX_OFF (NFRAG_BIG * 512)     // f16 offset of W_ih0 fragments

// Pack weights into MFMA B-fragment order: frag id f=(g*48+nt)*8+kt, each frag
// is 64 lanes x 8 f16 (lane gets W[n= nt*16+(lane&15)][k= kt*32+(lane>>4)*8 + j]).
__global__ void prep_weights(const float* __restrict__ Whh0,
                             const float* __restrict__ Wih1,
                             const float* __restrict__ Whh1,
                             const float* __restrict__ Wih0,
                             f16* __restrict__ ws) {
  int tid = blockIdx.x * blockDim.x + threadIdx.x;
  if (tid < NFRAG_BIG * 64) {
    int lane = tid & 63;
    int kt = (tid >> 6) & 7;
    int nt = (tid >> 9) % 48;
    int g = tid / (48 * 8 * 64);
    const float* W = (g == 0) ? Whh0 : (g == 1) ? Wih1 : Whh1;
    int n = nt * 16 + (lane & 15);
    int kb = kt * 32 + (lane >> 4) * 8;
    f16* dst = ws + (size_t)tid * 8;
#pragma unroll
    for (int j = 0; j < 8; ++j) dst[j] = (f16)W[n * H_ + kb + j];
  } else if (tid < NFRAG_BIG * 64 + 48 * 64) {
    int t2 = tid - NFRAG_BIG * 64;
    int lane = t2 & 63;
    int nt = t2 >> 6;
    int n = nt * 16 + (lane & 15);
    int kb = (lane >> 4) * 8;
    f16* dst = ws + WSX_OFF + (size_t)t2 * 8;
#pragma unroll
    for (int j = 0; j < 8; ++j) {
      int k = kb + j;
      dst[j] = (k < I_) ? (f16)Wih0[n * I_ + k] : (f16)0.f;  // zero-pad K 18->32
    }
  }
}

__device__ __forceinline__ float sigm(float v) {
  v = fminf(fmaxf(v, -30.f), 30.f);
  return __builtin_amdgcn_rcpf(1.f + __expf(-v));
}
__device__ __forceinline__ float tanh_fast(float v) {
  v = fminf(fmaxf(v, -15.f), 15.f);
  float e = __expf(-2.f * v);
  return (1.f - e) * __builtin_amdgcn_rcpf(1.f + e);
}

__device__ __forceinline__ f16x8 ldW(const f16* __restrict__ ws, int g, int nt,
                                     int kt, int lane) {
  return *(const f16x8*)(ws + ((((g * 48 + nt) * 8 + kt) << 9) + (lane << 3)));
}

// 64 blocks x 512 threads (8 waves). Block owns 16 batch rows; wave wv owns
// hidden cols [wv*32, wv*32+32) => gate n-tiles {gate*16 + wv*2 + tt}.
__global__ __launch_bounds__(512, 2) void gru_main(
    const float* __restrict__ x, const float* __restrict__ bih0,
    const float* __restrict__ bhh0, const float* __restrict__ bih1,
    const float* __restrict__ bhh1, const float* __restrict__ fcw,
    const float* __restrict__ fcb, const f16* __restrict__ ws,
    float* __restrict__ out) {
  __shared__ f16 h0l[16 * 256];   // XOR-swizzled f16 copies for the A operand
  __shared__ f16 h1l[16 * 256];
  __shared__ float hof[16 * 256]; // final h1 (fp32) for the fc head

  const int tid = threadIdx.x;
  const int wv = tid >> 6;
  const int lane = tid & 63;
  const int lrow = lane & 15;
  const int lgrp = lane >> 4;
  const int bc0 = blockIdx.x * 16;

  for (int i = tid; i < 16 * 256; i += 512) {
    h0l[i] = (f16)0.f;
    h1l[i] = (f16)0.f;
  }

  // Bias fragments (col depends only on lane&15): r/z combine b_ih+b_hh; n keeps split.
  float bR0[2], bZ0[2], bI0[2], bH0[2];
  float bR1[2], bZ1[2], bI1[2], bH1[2];
#pragma unroll
  for (int tt = 0; tt < 2; ++tt) {
    int c = (wv << 5) + (tt << 4) + lrow;
    bR0[tt] = bih0[c] + bhh0[c];
    bZ0[tt] = bih0[H_ + c] + bhh0[H_ + c];
    bI0[tt] = bih0[2 * H_ + c];
    bH0[tt] = bhh0[2 * H_ + c];
    bR1[tt] = bih1[c] + bhh1[c];
    bZ1[tt] = bih1[H_ + c] + bhh1[H_ + c];
    bI1[tt] = bih1[2 * H_ + c];
    bH1[tt] = bhh1[2 * H_ + c];
  }

  // W_ih0 fragments: tiny, register-resident for the whole kernel.
  f16x8 wx[3][2];
#pragma unroll
  for (int g = 0; g < 3; ++g)
#pragma unroll
    for (int tt = 0; tt < 2; ++tt) {
      int nt = g * 16 + (wv * 2 + tt);
      wx[g][tt] = *(const f16x8*)(ws + WSX_OFF + nt * 512 + lane * 8);
    }

  // h state (fp32) lives in registers at C/D fragment positions:
  // row=(lane>>4)*4+r, col=wv*32+tt*16+(lane&15)
  float h0r[2][4] = {{0.f, 0.f, 0.f, 0.f}, {0.f, 0.f, 0.f, 0.f}};
  float h1r[2][4] = {{0.f, 0.f, 0.f, 0.f}, {0.f, 0.f, 0.f, 0.f}};

  const float* xrow = x + (size_t)(bc0 + lrow) * T_ * I_;

  __syncthreads();

  for (int t = 0; t < T_; ++t) {
    // ================= Layer 0 =================
    f32x4 aR[2], aZ[2], aI[2], aH[2];
#pragma unroll
    for (int tt = 0; tt < 2; ++tt) {
      aR[tt] = (f32x4){bR0[tt], bR0[tt], bR0[tt], bR0[tt]};
      aZ[tt] = (f32x4){bZ0[tt], bZ0[tt], bZ0[tt], bZ0[tt]};
      aI[tt] = (f32x4){bI0[tt], bI0[tt], bI0[tt], bI0[tt]};
      aH[tt] = (f32x4){bH0[tt], bH0[tt], bH0[tt], bH0[tt]};
    }
    // x A-fragment (K=18 zero-padded to 32; pad lanes load 0 to match 0-weights)
    f16x8 ax;
    {
      const float* xp = xrow + (size_t)t * I_;
#pragma unroll
      for (int j = 0; j < 8; ++j) {
        int k = lgrp * 8 + j;
        ax[j] = (k < I_) ? (f16)xp[k] : (f16)0.f;
      }
    }
#pragma unroll
    for (int tt = 0; tt < 2; ++tt) {
      aR[tt] = MFMA16(ax, wx[0][tt], aR[tt]);
      aZ[tt] = MFMA16(ax, wx[1][tt], aZ[tt]);
      aI[tt] = MFMA16(ax, wx[2][tt], aI[tt]);
    }
#pragma unroll
    for (int kt = 0; kt < 8; ++kt) {
      f16x8 a0 = *(const f16x8*)&h0l[(lrow << 8) +
                                     (((kt << 5) + (lgrp << 3)) ^ ((lrow & 7) << 3))];
#pragma unroll
      for (int tt = 0; tt < 2; ++tt) {
        int ct = wv * 2 + tt;
        aR[tt] = MFMA16(a0, ldW(ws, 0, ct, kt, lane), aR[tt]);
        aZ[tt] = MFMA16(a0, ldW(ws, 0, 16 + ct, kt, lane), aZ[tt]);
        aH[tt] = MFMA16(a0, ldW(ws, 0, 32 + ct, kt, lane), aH[tt]);
      }
    }
#pragma unroll
    for (int tt = 0; tt < 2; ++tt)
#pragma unroll
      for (int r = 0; r < 4; ++r) {
        float rr = sigm(aR[tt][r]);
        float zz = sigm(aZ[tt][r]);
        float nn = tanh_fast(aI[tt][r] + rr * aH[tt][r]);
        h0r[tt][r] = (1.f - zz) * nn + zz * h0r[tt][r];
      }
    __syncthreads();  // B1: all h0l reads done
#pragma unroll
    for (int tt = 0; tt < 2; ++tt) {
      int col = (wv << 5) + (tt << 4) + lrow;
#pragma unroll
      for (int r = 0; r < 4; ++r) {
        int row = (lgrp << 2) + r;
        h0l[(row << 8) + (col ^ ((row & 7) << 3))] = (f16)h0r[tt][r];
      }
    }
    __syncthreads();  // B2: new h0 visible

    // ================= Layer 1 =================
#pragma unroll
    for (int tt = 0; tt < 2; ++tt) {
      aR[tt] = (f32x4){bR1[tt], bR1[tt], bR1[tt], bR1[tt]};
      aZ[tt] = (f32x4){bZ1[tt], bZ1[tt], bZ1[tt], bZ1[tt]};
      aI[tt] = (f32x4){bI1[tt], bI1[tt], bI1[tt], bI1[tt]};
      aH[tt] = (f32x4){bH1[tt], bH1[tt], bH1[tt], bH1[tt]};
    }
#pragma unroll
    for (int kt = 0; kt < 8; ++kt) {
      int off = (((kt << 5) + (lgrp << 3)) ^ ((lrow & 7) << 3));
      f16x8 a0 = *(const f16x8*)&h0l[(lrow << 8) + off];  // h0 (new)
      f16x8 a1 = *(const f16x8*)&h1l[(lrow << 8) + off];  // h1 (prev step)
#pragma unroll
      for (int tt = 0; tt < 2; ++tt) {
        int ct = wv * 2 + tt;
        aR[tt] = MFMA16(a0, ldW(ws, 1, ct, kt, lane), aR[tt]);
        aR[tt] = MFMA16(a1, ldW(ws, 2, ct, kt, lane), aR[tt]);
        aZ[tt] = MFMA16(a0, ldW(ws, 1, 16 + ct, kt, lane), aZ[tt]);
        aZ[tt] = MFMA16(a1, ldW(ws, 2, 16 + ct, kt, lane), aZ[tt]);
        aI[tt] = MFMA16(a0, ldW(ws, 1, 32 + ct, kt, lane), aI[tt]);
        aH[tt] = MFMA16(a1, ldW(ws, 2, 32 + ct, kt, lane), aH[tt]);
      }
    }
#pragma unroll
    for (int tt = 0; tt < 2; ++tt)
#pragma unroll
      for (int r = 0; r < 4; ++r) {
        float rr = sigm(aR[tt][r]);
        float zz = sigm(aZ[tt][r]);
        float nn = tanh_fast(aI[tt][r] + rr * aH[tt][r]);
        h1r[tt][r] = (1.f - zz) * nn + zz * h1r[tt][r];
      }
    __syncthreads();  // B3: all h1l reads done
#pragma unroll
    for (int tt = 0; tt < 2; ++tt) {
      int col = (wv << 5) + (tt << 4) + lrow;
#pragma unroll
      for (int r = 0; r < 4; ++r) {
        int row = (lgrp << 2) + r;
        h1l[(row << 8) + (col ^ ((row & 7) << 3))] = (f16)h1r[tt][r];
      }
    }
    __syncthreads();  // B4: new h1 visible
  }

  // ================= fc head =================
#pragma unroll
  for (int tt = 0; tt < 2; ++tt) {
    int col = (wv << 5) + (tt << 4) + lrow;
#pragma unroll
    for (int r = 0; r < 4; ++r) {
      int row = (lgrp << 2) + r;
      hof[(row << 8) + col] = h1r[tt][r];
    }
  }
  __syncthreads();
#pragma unroll
  for (int rr = 0; rr < 2; ++rr) {
    int row = wv * 2 + rr;
    float s = 0.f;
#pragma unroll
    for (int k4 = 0; k4 < 4; ++k4) {
      int k = k4 * 64 + lane;
      s += hof[(row << 8) + k] * fcw[k];
    }
#pragma unroll
    for (int off = 32; off; off >>= 1) s += __shfl_down(s, off);
    if (lane == 0) out[bc0 + row] = s + fcb[0];
  }
}

extern "C" void kernel_launch(void* const* d_in, const int* in_sizes, int n_in,
                              void* d_out, int out_size, void* d_ws, size_t ws_size,
                              hipStream_t stream) {
  const float* x    = (const float*)d_in[0];
  const float* Wih0 = (const float*)d_in[1];
  const float* Whh0 = (const float*)d_in[2];
  const float* bih0 = (const float*)d_in[3];
  const float* bhh0 = (const float*)d_in[4];
  const float* Wih1 = (const float*)d_in[5];
  const float* Whh1 = (const float*)d_in[6];
  const float* bih1 = (const float*)d_in[7];
  const float* bhh1 = (const float*)d_in[8];
  const float* fcw  = (const float*)d_in[9];
  const float* fcb  = (const float*)d_in[10];

  f16* ws = (f16*)d_ws;  // needs ~1.2 MB

  prep_weights<<<300, 256, 0, stream>>>(Whh0, Wih1, Whh1, Wih0, ws);
  gru_main<<<64, 512, 0, stream>>>(x, bih0, bhh0, bih1, bhh1, fcw, fcb, ws,
                                   (float*)d_out);
}

// Round 2
// 5569.929 us; speedup vs baseline: 7.9088x; 7.9088x over previous
//
#include <hip/hip_runtime.h>

#define B_ 1024
#define T_ 1024
#define I_ 18
#define H_ 256
#define NCHUNK 16
#define NSLICE 16

typedef _Float16 f16;
typedef _Float16 f16x8 __attribute__((ext_vector_type(8)));
typedef float f32x4 __attribute__((ext_vector_type(4)));

#define MFMA16(a, b, c) __builtin_amdgcn_mfma_f32_16x16x32_f16((a), (b), (c), 0, 0, 0)

// ---------------- ws layout (f16 units unless noted) ----------------
// weight fragments: per slice s: 75 frags x 512 f16 (1KB each)
//   frag order: ih0: g(3) [kt=0] | hh0: g*8+kt (24) | ih1: (24) | hh1: (24)
#define WF_FRAGS 75
#define WF_SLICE (WF_FRAGS * 512)
#define WF_TOTAL (NSLICE * WF_SLICE)          // 614400 f16 = 1.2 MB
#define HB0 WF_TOTAL                          // h fragment buffers
#define HB_TOTAL (2 * 2 * NCHUNK * 8 * 4 * 512)  // 1,048,576 f16 = 2 MB
#define PART_B ((HB0 + HB_TOTAL) * 2)         // byte offset: partials (1024x16 f32)
#define CTR_B (PART_B + 1024 * 16 * 4)        // byte offset: group counters
// register-resident frag ids
#define F_IH0(g) (g)
#define F_HH0(g, kt) (3 + (g) * 8 + (kt))
#define F_IH1(g, kt) (27 + (g) * 8 + (kt))
// hh1 lives in LDS (spill hedge): lds id = g*8+kt

__device__ __forceinline__ int hfrag(int layer, int par, int chunk, int kt, int m) {
  return ((((layer * 2 + par) * NCHUNK + chunk) * 8 + kt) * 4 + m) * 512;
}

__global__ void init_ws(f16* __restrict__ ws) {
  int i = blockIdx.x * blockDim.x + threadIdx.x;
  unsigned* hb = (unsigned*)(ws + HB0);
  for (int k = i; k < HB_TOTAL / 2; k += gridDim.x * blockDim.x) hb[k] = 0u;
  int* ctr = (int*)((char*)ws + CTR_B);
  if (i < NCHUNK * 16) ctr[i] = 0;
}

__global__ void prep_weights(const float* __restrict__ Wih0,
                             const float* __restrict__ Whh0,
                             const float* __restrict__ Wih1,
                             const float* __restrict__ Whh1,
                             f16* __restrict__ ws) {
  int tid = blockIdx.x * blockDim.x + threadIdx.x;
  if (tid >= NSLICE * WF_FRAGS * 64) return;
  int lane = tid & 63;
  int f = (tid >> 6) % WF_FRAGS;
  int s = tid / (WF_FRAGS * 64);
  int lrow = lane & 15, lgrp = lane >> 4;
  f16 v[8];
  if (f < 3) {  // W_ih0, K=18 zero-padded to 32
    int n = f * H_ + s * 16 + lrow;
#pragma unroll
    for (int j = 0; j < 8; ++j) {
      int k = lgrp * 8 + j;
      v[j] = (k < I_) ? (f16)Wih0[n * I_ + k] : (f16)0.f;
    }
  } else {
    int ff;
    const float* W;
    if (f < 27) { ff = f - 3;  W = Whh0; }
    else if (f < 51) { ff = f - 27; W = Wih1; }
    else { ff = f - 51; W = Whh1; }
    int g = ff >> 3, kt = ff & 7;
    int n = g * H_ + s * 16 + lrow;
    int kb = kt * 32 + lgrp * 8;
#pragma unroll
    for (int j = 0; j < 8; ++j) v[j] = (f16)W[n * H_ + kb + j];
  }
  *(f16x8*)(ws + ((size_t)s * WF_SLICE + f * 512 + lane * 8)) = *(f16x8*)v;
}

__device__ __forceinline__ float sigm(float v) {
  v = fminf(fmaxf(v, -30.f), 30.f);
  return __builtin_amdgcn_rcpf(1.f + __expf(-v));
}
__device__ __forceinline__ float tanh_fast(float v) {
  v = fminf(fmaxf(v, -15.f), 15.f);
  float e = __expf(-2.f * v);
  return (1.f - e) * __builtin_amdgcn_rcpf(1.f + e);
}

// device/system-coherent (MALL-routed) 16B load/store: correct across XCDs
__device__ __forceinline__ f16x8 ldg_sys(const f16* p) {
  f16x8 r;
  asm volatile("global_load_dwordx4 %0, %1, off sc0 sc1" : "=&v"(r) : "v"(p));
  return r;
}
__device__ __forceinline__ void stg_sys(f16* p, f16x8 v) {
  asm volatile("global_store_dwordx4 %0, %1, off sc0 sc1" ::"v"(p), "v"(v)
               : "memory");
}

// 256 blocks x 256 threads; block = (chunk = bx>>4, slice = bx&15).
// Registers (~350/wave) force 1 block/CU -> all 256 co-resident -> spin safe.
__global__ __launch_bounds__(256, 1) void gru_main(
    const float* __restrict__ x, const float* __restrict__ bih0,
    const float* __restrict__ bhh0, const float* __restrict__ bih1,
    const float* __restrict__ bhh1, const float* __restrict__ fcw,
    f16* __restrict__ ws) {
  __shared__ f16 whh1_l[24 * 512];  // 24KB: W_hh1 slice fragments
  __shared__ f16 hstage[2][64 * 16];  // 4KB: transpose staging

  const int tid = threadIdx.x;
  const int wv = tid >> 6, lane = tid & 63;
  const int lrow = lane & 15, lgrp = lane >> 4;
  const int chunk = blockIdx.x >> 4, slice = blockIdx.x & 15;

  // ---- load persistent weight fragments ----
  f16x8 wf[51];
  {
    const f16* wb = ws + (size_t)slice * WF_SLICE + lane * 8;
#pragma unroll
    for (int f = 0; f < 51; ++f) wf[f] = *(const f16x8*)(wb + f * 512);
  }
  for (int i = tid; i < 24 * 64; i += 256)
    ((f16x8*)whh1_l)[i] =
        ((const f16x8*)(ws + (size_t)slice * WF_SLICE + 51 * 512))[i];

  const int c = slice * 16 + lrow;  // this lane's h column
  const float bR0 = bih0[c] + bhh0[c], bZ0 = bih0[H_ + c] + bhh0[H_ + c];
  const float bI0 = bih0[2 * H_ + c], bH0 = bhh0[2 * H_ + c];
  const float bR1 = bih1[c] + bhh1[c], bZ1 = bih1[H_ + c] + bhh1[H_ + c];
  const float bI1 = bih1[2 * H_ + c], bH1 = bhh1[2 * H_ + c];
  const float fw = fcw[c];

  float h0r[4] = {0.f, 0.f, 0.f, 0.f}, h1r[4] = {0.f, 0.f, 0.f, 0.f};

  f16* hb = ws + HB0;
  int* ctr = (int*)((char*)ws + CTR_B) + chunk * 16;
  const int rbase = chunk * 64 + wv * 16;
  const float* xrow = x + (size_t)(rbase + lrow) * T_ * I_;
  int dead = 0;

  __syncthreads();

  for (int p = 0; p <= T_; ++p) {
    // ---- A-operand loads (coherent): h0(p-1), h1(p-2) ----
    f16x8 ah0[8], ah1[8];
    {
      const f16* b0 = hb + hfrag(0, (p + 1) & 1, chunk, 0, wv) + lane * 8;
      const f16* b1 = hb + hfrag(1, p & 1, chunk, 0, wv) + lane * 8;
#pragma unroll
      for (int kt = 0; kt < 8; ++kt) ah0[kt] = ldg_sys(b0 + kt * 2048);
#pragma unroll
      for (int kt = 0; kt < 8; ++kt) ah1[kt] = ldg_sys(b1 + kt * 2048);
    }
    // ---- x fragment (plain cached loads) ----
    f16x8 ax;
#pragma unroll
    for (int j = 0; j < 8; ++j) {
      int k = lgrp * 8 + j;
      float xv = (p < T_ && k < I_) ? xrow[(size_t)p * I_ + k] : 0.f;
      ax[j] = (f16)xv;
    }
    asm volatile("s_waitcnt vmcnt(0)" ::: "memory");
    __builtin_amdgcn_sched_barrier(0);

    // ---- MFMAs ----
    f32x4 aR0 = {bR0, bR0, bR0, bR0}, aZ0 = {bZ0, bZ0, bZ0, bZ0};
    f32x4 aI0 = {bI0, bI0, bI0, bI0}, aH0 = {bH0, bH0, bH0, bH0};
    f32x4 aR1 = {bR1, bR1, bR1, bR1}, aZ1 = {bZ1, bZ1, bZ1, bZ1};
    f32x4 aI1 = {bI1, bI1, bI1, bI1}, aH1 = {bH1, bH1, bH1, bH1};
    aR0 = MFMA16(ax, wf[F_IH0(0)], aR0);
    aZ0 = MFMA16(ax, wf[F_IH0(1)], aZ0);
    aI0 = MFMA16(ax, wf[F_IH0(2)], aI0);
#pragma unroll
    for (int kt = 0; kt < 8; ++kt) {
      f16x8 bh1r = *(const f16x8*)&whh1_l[(0 * 8 + kt) * 512 + lane * 8];
      f16x8 bh1z = *(const f16x8*)&whh1_l[(1 * 8 + kt) * 512 + lane * 8];
      f16x8 bh1n = *(const f16x8*)&whh1_l[(2 * 8 + kt) * 512 + lane * 8];
      aR0 = MFMA16(ah0[kt], wf[F_HH0(0, kt)], aR0);
      aZ0 = MFMA16(ah0[kt], wf[F_HH0(1, kt)], aZ0);
      aH0 = MFMA16(ah0[kt], wf[F_HH0(2, kt)], aH0);
      aR1 = MFMA16(ah0[kt], wf[F_IH1(0, kt)], aR1);
      aZ1 = MFMA16(ah0[kt], wf[F_IH1(1, kt)], aZ1);
      aI1 = MFMA16(ah0[kt], wf[F_IH1(2, kt)], aI1);
      aR1 = MFMA16(ah1[kt], bh1r, aR1);
      aZ1 = MFMA16(ah1[kt], bh1z, aZ1);
      aH1 = MFMA16(ah1[kt], bh1n, aH1);
    }

    // ---- GRU updates + LDS transpose staging ----
    if (p < T_) {
#pragma unroll
      for (int i = 0; i < 4; ++i) {
        float rr = sigm(aR0[i]);
        float zz = sigm(aZ0[i]);
        float nn = tanh_fast(aI0[i] + rr * aH0[i]);
        h0r[i] = (1.f - zz) * nn + zz * h0r[i];
        hstage[0][(wv * 16 + lgrp * 4 + i) * 16 + lrow] = (f16)h0r[i];
      }
    }
    if (p > 0) {
#pragma unroll
      for (int i = 0; i < 4; ++i) {
        float rr = sigm(aR1[i]);
        float zz = sigm(aZ1[i]);
        float nn = tanh_fast(aI1[i] + rr * aH1[i]);
        h1r[i] = (1.f - zz) * nn + zz * h1r[i];
        hstage[1][(wv * 16 + lgrp * 4 + i) * 16 + lrow] = (f16)h1r[i];
      }
    }
    __syncthreads();

    // ---- scatter staged h to global A-fragment layout (coherent stores) ----
    {
      int lay = tid >> 7;
      int row = (tid >> 1) & 63;
      int half = tid & 1;
      bool doit = lay ? (p > 0) : (p < T_);
      if (doit) {
        f16x8 v = *(const f16x8*)&hstage[lay][row * 16 + half * 8];
        int kt = slice >> 1;
        int lgt = (slice & 1) * 2 + half;
        int lt = (row & 15) + 16 * lgt;
        int m = row >> 4;
        int par = lay ? ((p + 1) & 1) : (p & 1);
        stg_sys(hb + hfrag(lay, par, chunk, kt, m) + lt * 8, v);
      }
    }
    asm volatile("s_waitcnt vmcnt(0)" ::: "memory");
    __syncthreads();

    // ---- group barrier: 16 blocks of this chunk ----
    if (tid == 0 && !dead) {
      __hip_atomic_fetch_add(ctr, 1, __ATOMIC_RELAXED, __HIP_MEMORY_SCOPE_AGENT);
      int tgt = 16 * (p + 1);
      int guard = 0;
      while (__hip_atomic_load(ctr, __ATOMIC_RELAXED,
                               __HIP_MEMORY_SCOPE_AGENT) < tgt) {
        if (++guard > (1 << 20)) { dead = 1; break; }  // bail, never hang
      }
    }
    __syncthreads();
  }

  // ---- fc head partials: out_row partial = sum over this slice's 16 cols ----
  float tmp[4];
#pragma unroll
  for (int i = 0; i < 4; ++i) {
    float v = h1r[i] * fw;
#pragma unroll
    for (int m = 1; m < 16; m <<= 1) v += __shfl_xor(v, m);
    tmp[i] = v;
  }
  if (lrow == 0) {
    float* part = (float*)((char*)ws + PART_B);
#pragma unroll
    for (int i = 0; i < 4; ++i)
      part[(size_t)(rbase + lgrp * 4 + i) * 16 + slice] = tmp[i];
  }
}

__global__ void fc_reduce(const f16* __restrict__ ws,
                          const float* __restrict__ fcb,
                          float* __restrict__ out) {
  int r = blockIdx.x * blockDim.x + threadIdx.x;
  if (r < B_) {
    const float* part = (const float*)((const char*)ws + PART_B);
    float s = fcb[0];
#pragma unroll
    for (int i = 0; i < 16; ++i) s += part[r * 16 + i];
    out[r] = s;
  }
}

extern "C" void kernel_launch(void* const* d_in, const int* in_sizes, int n_in,
                              void* d_out, int out_size, void* d_ws, size_t ws_size,
                              hipStream_t stream) {
  const float* x    = (const float*)d_in[0];
  const float* Wih0 = (const float*)d_in[1];
  const float* Whh0 = (const float*)d_in[2];
  const float* bih0 = (const float*)d_in[3];
  const float* bhh0 = (const float*)d_in[4];
  const float* Wih1 = (const float*)d_in[5];
  const float* Whh1 = (const float*)d_in[6];
  const float* bih1 = (const float*)d_in[7];
  const float* bhh1 = (const float*)d_in[8];
  const float* fcw  = (const float*)d_in[9];
  const float* fcb  = (const float*)d_in[10];

  f16* ws = (f16*)d_ws;  // needs ~3.3 MB

  init_ws<<<1024, 256, 0, stream>>>(ws);
  prep_weights<<<300, 256, 0, stream>>>(Wih0, Whh0, Wih1, Whh1, ws);
  gru_main<<<256, 256, 0, stream>>>(x, bih0, bhh0, bih1, bhh1, fcw, ws);
  fc_reduce<<<4, 256, 0, stream>>>(ws, fcb, (float*)d_out);
}

// Round 3
// 4402.352 us; speedup vs baseline: 10.0064x; 1.2652x over previous
//
#include <hip/hip_runtime.h>

#define B_ 1024
#define T_ 1024
#define I_ 18
#define H_ 256
#define NCHUNK 16
#define NSLICE 16

typedef _Float16 f16;
typedef _Float16 f16x8 __attribute__((ext_vector_type(8)));
typedef float f32x4 __attribute__((ext_vector_type(4)));

#define MFMA16(a, b, c) __builtin_amdgcn_mfma_f32_16x16x32_f16((a), (b), (c), 0, 0, 0)

// ---------------- ws layout ----------------
#define WF_FRAGS 75
#define WF_SLICE (WF_FRAGS * 512)
#define WF_TOTAL (NSLICE * WF_SLICE)             // 1.2 MB (f16)
#define HB0 WF_TOTAL
#define HB_TOTAL (2 * 2 * NCHUNK * 8 * 4 * 512)  // 2 MB (f16)
#define PART_B ((HB0 + HB_TOTAL) * 2)            // partials: 1024x16 f32
#define FLAG_B (PART_B + 1024 * 16 * 4)          // flags: [chunk][wave][16] ints
#define F_IH0(g) (g)
#define F_HH0(g, kt) (3 + (g) * 8 + (kt))
#define F_IH1(g, kt) (27 + (g) * 8 + (kt))

__device__ __forceinline__ int hfrag(int layer, int par, int chunk, int kt, int m) {
  return ((((layer * 2 + par) * NCHUNK + chunk) * 8 + kt) * 4 + m) * 512;
}

__global__ void init_ws(f16* __restrict__ ws) {
  int i = blockIdx.x * blockDim.x + threadIdx.x;
  unsigned* hb = (unsigned*)(ws + HB0);
  for (int k = i; k < HB_TOTAL / 2; k += gridDim.x * blockDim.x) hb[k] = 0u;
  int* flg = (int*)((char*)ws + FLAG_B);
  if (i < NCHUNK * 4 * 16) flg[i] = 0;
}

__global__ void prep_weights(const float* __restrict__ Wih0,
                             const float* __restrict__ Whh0,
                             const float* __restrict__ Wih1,
                             const float* __restrict__ Whh1,
                             f16* __restrict__ ws) {
  int tid = blockIdx.x * blockDim.x + threadIdx.x;
  if (tid >= NSLICE * WF_FRAGS * 64) return;
  int lane = tid & 63;
  int f = (tid >> 6) % WF_FRAGS;
  int s = tid / (WF_FRAGS * 64);
  int lrow = lane & 15, lgrp = lane >> 4;
  f16 v[8];
  if (f < 3) {  // W_ih0, K=18 zero-padded to 32
    int n = f * H_ + s * 16 + lrow;
#pragma unroll
    for (int j = 0; j < 8; ++j) {
      int k = lgrp * 8 + j;
      v[j] = (k < I_) ? (f16)Wih0[n * I_ + k] : (f16)0.f;
    }
  } else {
    int ff;
    const float* W;
    if (f < 27) { ff = f - 3;  W = Whh0; }
    else if (f < 51) { ff = f - 27; W = Wih1; }
    else { ff = f - 51; W = Whh1; }
    int g = ff >> 3, kt = ff & 7;
    int n = g * H_ + s * 16 + lrow;
    int kb = kt * 32 + lgrp * 8;
#pragma unroll
    for (int j = 0; j < 8; ++j) v[j] = (f16)W[n * H_ + kb + j];
  }
  *(f16x8*)(ws + ((size_t)s * WF_SLICE + f * 512 + lane * 8)) = *(f16x8*)v;
}

__device__ __forceinline__ float sigm(float v) {
  v = fminf(fmaxf(v, -30.f), 30.f);
  return __builtin_amdgcn_rcpf(1.f + __expf(-v));
}
__device__ __forceinline__ float tanh_fast(float v) {
  v = fminf(fmaxf(v, -15.f), 15.f);
  float e = __expf(-2.f * v);
  return (1.f - e) * __builtin_amdgcn_rcpf(1.f + e);
}

// MALL-coherent accesses (correct across XCDs)
__device__ __forceinline__ f16x8 ldg_sys(const f16* p) {
  f16x8 r;
  asm volatile("global_load_dwordx4 %0, %1, off sc0 sc1" : "=&v"(r) : "v"(p));
  return r;
}
__device__ __forceinline__ void stg_sys_h(f16* p, f16 v) {
  unsigned u = (unsigned)__builtin_bit_cast(unsigned short, v);
  asm volatile("global_store_short %0, %1, off sc0 sc1" ::"v"(p), "v"(u)
               : "memory");
}
__device__ __forceinline__ int ld_flag(const int* p) {
  int r;
  asm volatile("global_load_dword %0, %1, off sc0 sc1\n\ts_waitcnt vmcnt(0)"
               : "=&v"(r) : "v"(p) : "memory");
  return r;
}
__device__ __forceinline__ void st_flag(int* p, int v) {
  asm volatile("global_store_dword %0, %1, off sc0 sc1" ::"v"(p), "v"(v)
               : "memory");
}

// 256 blocks x 256 threads; block = (chunk = bx>>4, slice = bx&15).
// Wave (c,s,w) depends only on waves (c,*,w): per-wave flags, no __syncthreads
// in the main loop, no atomic RMW anywhere.
__global__ __launch_bounds__(256, 1) void gru_main(
    const float* __restrict__ x, const float* __restrict__ bih0,
    const float* __restrict__ bhh0, const float* __restrict__ bih1,
    const float* __restrict__ bhh1, const float* __restrict__ fcw,
    f16* __restrict__ ws) {
  __shared__ f16 whh1_l[24 * 512];  // 24KB: W_hh1 slice fragments

  const int tid = threadIdx.x;
  const int wv = tid >> 6, lane = tid & 63;
  const int lrow = lane & 15, lgrp = lane >> 4;
  const int chunk = blockIdx.x >> 4, slice = blockIdx.x & 15;

  // ---- persistent weight fragments ----
  f16x8 wf[51];
  {
    const f16* wb = ws + (size_t)slice * WF_SLICE + lane * 8;
#pragma unroll
    for (int f = 0; f < 51; ++f) wf[f] = *(const f16x8*)(wb + f * 512);
  }
  for (int i = tid; i < 24 * 64; i += 256)
    ((f16x8*)whh1_l)[i] =
        ((const f16x8*)(ws + (size_t)slice * WF_SLICE + 51 * 512))[i];

  const int c = slice * 16 + lrow;
  const float bR0 = bih0[c] + bhh0[c], bZ0 = bih0[H_ + c] + bhh0[H_ + c];
  const float bI0 = bih0[2 * H_ + c], bH0 = bhh0[2 * H_ + c];
  const float bR1 = bih1[c] + bhh1[c], bZ1 = bih1[H_ + c] + bhh1[H_ + c];
  const float bI1 = bih1[2 * H_ + c], bH1 = bhh1[2 * H_ + c];
  const float fw = fcw[c];

  float h0r[4] = {0.f, 0.f, 0.f, 0.f}, h1r[4] = {0.f, 0.f, 0.f, 0.f};

  f16* hb = ws + HB0;
  int* flags = (int*)((char*)ws + FLAG_B);
  const int* fpoll = flags + (chunk * 4 + wv) * 16 + lrow;  // lanes poll all 16
  int* fpost = flags + (chunk * 4 + wv) * 16 + slice;
  const int rbase = chunk * 64 + wv * 16;
  const float* xrow = x + (size_t)(rbase + lrow) * T_ * I_;
  // direct h-store addressing (fragment layout, verified == old scatter)
  const int s_kt = slice >> 1;
  const int s_off = 128 * ((slice & 1) * 2 + (lrow >> 3)) + (lrow & 7);
  int dead = 0;

  __syncthreads();  // whh1_l ready (only barrier in the kernel)

  for (int p = 0; p <= T_; ++p) {
    // ---- x prefetch (plain cached loads; completes during poll) ----
    f16x8 ax;
#pragma unroll
    for (int j = 0; j < 8; ++j) {
      int k = lgrp * 8 + j;
      float xv = (p < T_ && k < I_) ? xrow[(size_t)p * I_ + k] : 0.f;
      ax[j] = (f16)xv;
    }
    // ---- wait: all 16 same-w waves of this chunk finished phase p-1 ----
    if (p > 0 && !dead) {
      int guard = 0;
      for (;;) {
        int v = ld_flag(fpoll);
        if (__all(v >= p)) break;
        if (++guard > (1 << 18)) { dead = 1; break; }  // bail, never hang
        __builtin_amdgcn_s_sleep(2);
      }
    }
    __builtin_amdgcn_sched_barrier(0);

    // ---- A-operand loads: h0(p-1), h1(p-2) ----
    f16x8 ah0[8], ah1[8];
    {
      const f16* b0 = hb + hfrag(0, (p + 1) & 1, chunk, 0, wv) + lane * 8;
      const f16* b1 = hb + hfrag(1, p & 1, chunk, 0, wv) + lane * 8;
#pragma unroll
      for (int kt = 0; kt < 8; ++kt) ah0[kt] = ldg_sys(b0 + kt * 2048);
#pragma unroll
      for (int kt = 0; kt < 8; ++kt) ah1[kt] = ldg_sys(b1 + kt * 2048);
    }
    asm volatile("s_waitcnt vmcnt(0)" ::: "memory");
    __builtin_amdgcn_sched_barrier(0);

    // ---- MFMAs ----
    f32x4 aR0 = {bR0, bR0, bR0, bR0}, aZ0 = {bZ0, bZ0, bZ0, bZ0};
    f32x4 aI0 = {bI0, bI0, bI0, bI0}, aH0 = {bH0, bH0, bH0, bH0};
    f32x4 aR1 = {bR1, bR1, bR1, bR1}, aZ1 = {bZ1, bZ1, bZ1, bZ1};
    f32x4 aI1 = {bI1, bI1, bI1, bI1}, aH1 = {bH1, bH1, bH1, bH1};
    aR0 = MFMA16(ax, wf[F_IH0(0)], aR0);
    aZ0 = MFMA16(ax, wf[F_IH0(1)], aZ0);
    aI0 = MFMA16(ax, wf[F_IH0(2)], aI0);
#pragma unroll
    for (int kt = 0; kt < 8; ++kt) {
      f16x8 bh1r = *(const f16x8*)&whh1_l[(0 * 8 + kt) * 512 + lane * 8];
      f16x8 bh1z = *(const f16x8*)&whh1_l[(1 * 8 + kt) * 512 + lane * 8];
      f16x8 bh1n = *(const f16x8*)&whh1_l[(2 * 8 + kt) * 512 + lane * 8];
      aR0 = MFMA16(ah0[kt], wf[F_HH0(0, kt)], aR0);
      aZ0 = MFMA16(ah0[kt], wf[F_HH0(1, kt)], aZ0);
      aH0 = MFMA16(ah0[kt], wf[F_HH0(2, kt)], aH0);
      aR1 = MFMA16(ah0[kt], wf[F_IH1(0, kt)], aR1);
      aZ1 = MFMA16(ah0[kt], wf[F_IH1(1, kt)], aZ1);
      aI1 = MFMA16(ah0[kt], wf[F_IH1(2, kt)], aI1);
      aR1 = MFMA16(ah1[kt], bh1r, aR1);
      aZ1 = MFMA16(ah1[kt], bh1z, aZ1);
      aH1 = MFMA16(ah1[kt], bh1n, aH1);
    }

    // ---- GRU updates + direct fragment-layout stores (no LDS staging) ----
    if (p < T_) {
      f16* d0 = hb + hfrag(0, p & 1, chunk, s_kt, wv) + s_off;
#pragma unroll
      for (int i = 0; i < 4; ++i) {
        float rr = sigm(aR0[i]);
        float zz = sigm(aZ0[i]);
        float nn = tanh_fast(aI0[i] + rr * aH0[i]);
        h0r[i] = (1.f - zz) * nn + zz * h0r[i];
        stg_sys_h(d0 + (lgrp * 4 + i) * 8, (f16)h0r[i]);
      }
    }
    if (p > 0) {
      f16* d1 = hb + hfrag(1, (p + 1) & 1, chunk, s_kt, wv) + s_off;
#pragma unroll
      for (int i = 0; i < 4; ++i) {
        float rr = sigm(aR1[i]);
        float zz = sigm(aZ1[i]);
        float nn = tanh_fast(aI1[i] + rr * aH1[i]);
        h1r[i] = (1.f - zz) * nn + zz * h1r[i];
        stg_sys_h(d1 + (lgrp * 4 + i) * 8, (f16)h1r[i]);
      }
    }
    // ---- publish: data at MALL, then monotonic flag store (no RMW) ----
    asm volatile("s_waitcnt vmcnt(0)" ::: "memory");
    if (lane == 0) st_flag(fpost, p + 1);
  }

  // ---- fc head partials ----
  float tmp[4];
#pragma unroll
  for (int i = 0; i < 4; ++i) {
    float v = h1r[i] * fw;
#pragma unroll
    for (int m = 1; m < 16; m <<= 1) v += __shfl_xor(v, m);
    tmp[i] = v;
  }
  if (lrow == 0) {
    float* part = (float*)((char*)ws + PART_B);
#pragma unroll
    for (int i = 0; i < 4; ++i)
      part[(size_t)(rbase + lgrp * 4 + i) * 16 + slice] = tmp[i];
  }
}

__global__ void fc_reduce(const f16* __restrict__ ws,
                          const float* __restrict__ fcb,
                          float* __restrict__ out) {
  int r = blockIdx.x * blockDim.x + threadIdx.x;
  if (r < B_) {
    const float* part = (const float*)((const char*)ws + PART_B);
    float s = fcb[0];
#pragma unroll
    for (int i = 0; i < 16; ++i) s += part[r * 16 + i];
    out[r] = s;
  }
}

extern "C" void kernel_launch(void* const* d_in, const int* in_sizes, int n_in,
                              void* d_out, int out_size, void* d_ws, size_t ws_size,
                              hipStream_t stream) {
  const float* x    = (const float*)d_in[0];
  const float* Wih0 = (const float*)d_in[1];
  const float* Whh0 = (const float*)d_in[2];
  const float* bih0 = (const float*)d_in[3];
  const float* bhh0 = (const float*)d_in[4];
  const float* Wih1 = (const float*)d_in[5];
  const float* Whh1 = (const float*)d_in[6];
  const float* bih1 = (const float*)d_in[7];
  const float* bhh1 = (const float*)d_in[8];
  const float* fcw  = (const float*)d_in[9];
  const float* fcb  = (const float*)d_in[10];

  f16* ws = (f16*)d_ws;  // ~3.4 MB

  init_ws<<<1024, 256, 0, stream>>>(ws);
  prep_weights<<<300, 256, 0, stream>>>(Wih0, Whh0, Wih1, Whh1, ws);
  gru_main<<<256, 256, 0, stream>>>(x, bih0, bhh0, bih1, bhh1, fcw, ws);
  fc_reduce<<<4, 256, 0, stream>>>(ws, fcb, (float*)d_out);
}

// Round 4
// 2570.970 us; speedup vs baseline: 17.1342x; 1.7123x over previous
//
#include <hip/hip_runtime.h>

#define B_ 1024
#define T_ 1024
#define I_ 18
#define H_ 256
#define NCHUNK 16
#define NSLICE 16

typedef _Float16 f16;
typedef _Float16 f16x8 __attribute__((ext_vector_type(8)));
typedef float f32x4 __attribute__((ext_vector_type(4)));

#define MFMA16(a, b, c) __builtin_amdgcn_mfma_f32_16x16x32_f16((a), (b), (c), 0, 0, 0)

// ---------------- ws layout ----------------
#define WF_FRAGS 75
#define WF_SLICE (WF_FRAGS * 512)
#define WF_TOTAL (NSLICE * WF_SLICE)             // 1.2 MB (f16)
#define HB0 WF_TOTAL
#define HB_TOTAL (2 * 2 * NCHUNK * 8 * 4 * 512)  // 2 MB (f16)
#define PART_B ((HB0 + HB_TOTAL) * 2)            // partials: 1024x16 f32
#define FLAG_B (PART_B + 1024 * 16 * 4)          // flags: [chunk][wave][16]
#define IDS_B (FLAG_B + NCHUNK * 4 * 16 * 4)     // 256 xcc ids
#define DEC_B (IDS_B + 256 * 4)                  // 1 decision word
#define F_IH0(g) (g)
#define F_HH0(g, kt) (3 + (g) * 8 + (kt))
#define F_IH1(g, kt) (27 + (g) * 8 + (kt))
#define F_HH1(g, kt) (51 + (g) * 8 + (kt))

struct TrueT { static constexpr bool value = true; };
struct FalseT { static constexpr bool value = false; };

__device__ __forceinline__ int hfrag(int layer, int par, int chunk, int kt, int m) {
  return ((((layer * 2 + par) * NCHUNK + chunk) * 8 + kt) * 4 + m) * 512;
}

__global__ void init_ws(f16* __restrict__ ws) {
  int i = blockIdx.x * blockDim.x + threadIdx.x;
  unsigned* hb = (unsigned*)(ws + HB0);
  for (int k = i; k < HB_TOTAL / 2; k += gridDim.x * blockDim.x) hb[k] = 0u;
  int* flg = (int*)((char*)ws + FLAG_B);
  if (i < NCHUNK * 4 * 16 + 256 + 1) flg[i] = 0;  // flags + ids + decision
}

__global__ void prep_weights(const float* __restrict__ Wih0,
                             const float* __restrict__ Whh0,
                             const float* __restrict__ Wih1,
                             const float* __restrict__ Whh1,
                             f16* __restrict__ ws) {
  int tid = blockIdx.x * blockDim.x + threadIdx.x;
  if (tid >= NSLICE * WF_FRAGS * 64) return;
  int lane = tid & 63;
  int f = (tid >> 6) % WF_FRAGS;
  int s = tid / (WF_FRAGS * 64);
  int lrow = lane & 15, lgrp = lane >> 4;
  f16 v[8];
  if (f < 3) {  // W_ih0, K=18 zero-padded to 32
    int n = f * H_ + s * 16 + lrow;
#pragma unroll
    for (int j = 0; j < 8; ++j) {
      int k = lgrp * 8 + j;
      v[j] = (k < I_) ? (f16)Wih0[n * I_ + k] : (f16)0.f;
    }
  } else {
    int ff;
    const float* W;
    if (f < 27) { ff = f - 3;  W = Whh0; }
    else if (f < 51) { ff = f - 27; W = Wih1; }
    else { ff = f - 51; W = Whh1; }
    int g = ff >> 3, kt = ff & 7;
    int n = g * H_ + s * 16 + lrow;
    int kb = kt * 32 + lgrp * 8;
#pragma unroll
    for (int j = 0; j < 8; ++j) v[j] = (f16)W[n * H_ + kb + j];
  }
  *(f16x8*)(ws + ((size_t)s * WF_SLICE + f * 512 + lane * 8)) = *(f16x8*)v;
}

__device__ __forceinline__ float sigm(float v) {
  v = fminf(fmaxf(v, -30.f), 30.f);
  return __builtin_amdgcn_rcpf(1.f + __expf(-v));
}
__device__ __forceinline__ float tanh_fast(float v) {
  v = fminf(fmaxf(v, -15.f), 15.f);
  float e = __expf(-2.f * v);
  return (1.f - e) * __builtin_amdgcn_rcpf(1.f + e);
}

// FAST = XCD-local L2 path (plain WT stores, nt loads).
// slow = MALL-coherent sc0 sc1 path (cross-XCD correct).
template <bool FAST>
__device__ __forceinline__ f16x8 ldh(const f16* p) {
  f16x8 r;
  if (FAST)
    asm volatile("global_load_dwordx4 %0, %1, off nt" : "=&v"(r) : "v"(p));
  else
    asm volatile("global_load_dwordx4 %0, %1, off sc0 sc1" : "=&v"(r) : "v"(p));
  return r;
}
template <bool FAST>
__device__ __forceinline__ void sth(f16* p, f16 v) {
  unsigned u = (unsigned)__builtin_bit_cast(unsigned short, v);
  if (FAST)
    asm volatile("global_store_short %0, %1, off" ::"v"(p), "v"(u) : "memory");
  else
    asm volatile("global_store_short %0, %1, off sc0 sc1" ::"v"(p), "v"(u)
                 : "memory");
}
template <bool FAST>
__device__ __forceinline__ int ldf(const int* p) {
  int r;
  if (FAST)
    asm volatile("global_load_dword %0, %1, off nt\n\ts_waitcnt vmcnt(0)"
                 : "=&v"(r) : "v"(p) : "memory");
  else
    asm volatile("global_load_dword %0, %1, off sc0 sc1\n\ts_waitcnt vmcnt(0)"
                 : "=&v"(r) : "v"(p) : "memory");
  return r;
}
template <bool FAST>
__device__ __forceinline__ void stf(int* p, int v) {
  if (FAST)
    asm volatile("global_store_dword %0, %1, off" ::"v"(p), "v"(v) : "memory");
  else
    asm volatile("global_store_dword %0, %1, off sc0 sc1" ::"v"(p), "v"(v)
                 : "memory");
}
// always-MALL variants for the id/decision handshake
__device__ __forceinline__ int ld_sys(const int* p) { return ldf<false>(p); }
__device__ __forceinline__ void st_sys(int* p, int v) { stf<false>(p, v); }

// 256 blocks x 256 threads; chunk = blockIdx&15 (=> all 16 slice-blocks of a
// chunk share an XCD under round-robin b%8), slice = blockIdx>>4.
__global__ __launch_bounds__(256, 1) void gru_main(
    const float* __restrict__ x, const float* __restrict__ bih0,
    const float* __restrict__ bhh0, const float* __restrict__ bih1,
    const float* __restrict__ bhh1, const float* __restrict__ fcw,
    f16* __restrict__ ws) {
  const int tid = threadIdx.x;
  const int wv = tid >> 6, lane = tid & 63;
  const int lrow = lane & 15, lgrp = lane >> 4;
  const int chunk = blockIdx.x & 15, slice = blockIdx.x >> 4;

  // ---- all 75 weight fragments register/AGPR-resident (indices static) ----
  f16x8 wf[WF_FRAGS];
  {
    const f16* wb = ws + (size_t)slice * WF_SLICE + lane * 8;
#pragma unroll
    for (int f = 0; f < WF_FRAGS; ++f) wf[f] = *(const f16x8*)(wb + f * 512);
  }

  const int c = slice * 16 + lrow;
  const float bR0 = bih0[c] + bhh0[c], bZ0 = bih0[H_ + c] + bhh0[H_ + c];
  const float bI0 = bih0[2 * H_ + c], bH0 = bhh0[2 * H_ + c];
  const float bR1 = bih1[c] + bhh1[c], bZ1 = bih1[H_ + c] + bhh1[H_ + c];
  const float bI1 = bih1[2 * H_ + c], bH1 = bhh1[2 * H_ + c];
  const float fw = fcw[c];

  float h0r[4] = {0.f, 0.f, 0.f, 0.f}, h1r[4] = {0.f, 0.f, 0.f, 0.f};

  f16* hb = ws + HB0;
  int* flags = (int*)((char*)ws + FLAG_B);
  const int* fpoll = flags + (chunk * 4 + wv) * 16 + lrow;
  int* fpost = flags + (chunk * 4 + wv) * 16 + slice;
  int* ids = (int*)((char*)ws + IDS_B);
  int* dec = (int*)((char*)ws + DEC_B);
  const int rbase = chunk * 64 + wv * 16;
  const float* xrow = x + (size_t)(rbase + lrow) * T_ * I_;
  const int s_kt = slice >> 1;
  const int s_off = 128 * ((slice & 1) * 2 + (lrow >> 3)) + (lrow & 7);
  int dead = 0;

  // ---- runtime XCD-placement verification -> global fast/slow decision ----
  {
    unsigned xcc;
    asm volatile("s_getreg_b32 %0, hwreg(HW_REG_XCC_ID)" : "=s"(xcc));
    if (tid == 0) st_sys(ids + blockIdx.x, (int)xcc + 1);
    if (blockIdx.x == 0 && wv == 0) {
      int ok, guard = 0;
      for (;;) {
        int v0 = ld_sys(ids + lane * 4 + 0), v1 = ld_sys(ids + lane * 4 + 1);
        int v2 = ld_sys(ids + lane * 4 + 2), v3 = ld_sys(ids + lane * 4 + 3);
        ok = (v0 && v1 && v2 && v3);
        if (__all(ok)) { ok = 1; break; }
        if (++guard > (1 << 16)) { ok = 0; break; }
        __builtin_amdgcn_s_sleep(8);
      }
      int verdict = 1;
      if (ok) {
        int eq = 1;
        if (lane < 16) {  // lane = chunk id; blocks of chunk: s*16 + lane
          int r0 = ld_sys(ids + lane);
          for (int s = 1; s < 16; ++s)
            eq &= (ld_sys(ids + s * 16 + lane) == r0);
        }
        verdict = __all(eq) ? 2 : 1;
      }
      if (lane == 0) st_sys(dec, verdict);
    }
  }
  int decision = 1;
  {
    int g = 0;
    for (;;) {
      int d = ld_sys(dec);
      if (d) { decision = d; break; }
      if (++g > (1 << 20)) break;
      __builtin_amdgcn_s_sleep(8);
    }
  }

  auto phase_loop = [&](auto FC) {
    constexpr bool F = decltype(FC)::value;
    for (int p = 0; p <= T_; ++p) {
      // x prefetch (plain cached; drains during first poll iteration)
      f16x8 ax;
#pragma unroll
      for (int j = 0; j < 8; ++j) {
        int k = lgrp * 8 + j;
        float xv = (p < T_ && k < I_) ? xrow[(size_t)p * I_ + k] : 0.f;
        ax[j] = (f16)xv;
      }
      if (p > 0 && !dead) {
        int guard = 0;
        for (;;) {
          int v = ldf<F>(fpoll);
          if (__all(v >= p)) break;
          if (++guard > (1 << 18)) { dead = 1; break; }
          __builtin_amdgcn_s_sleep(1);
        }
      }
      __builtin_amdgcn_sched_barrier(0);

      // h loads: h0(p-1), h1(p-2)
      f16x8 ah0[8], ah1[8];
      {
        const f16* b0 = hb + hfrag(0, (p + 1) & 1, chunk, 0, wv) + lane * 8;
        const f16* b1 = hb + hfrag(1, p & 1, chunk, 0, wv) + lane * 8;
#pragma unroll
        for (int kt = 0; kt < 8; ++kt) ah0[kt] = ldh<F>(b0 + kt * 2048);
#pragma unroll
        for (int kt = 0; kt < 8; ++kt) ah1[kt] = ldh<F>(b1 + kt * 2048);
      }
      __builtin_amdgcn_sched_barrier(0);
      asm volatile("s_waitcnt vmcnt(8)" ::: "memory");  // ah0 ready
      __builtin_amdgcn_sched_barrier(0);

      f32x4 aR0 = {bR0, bR0, bR0, bR0}, aZ0 = {bZ0, bZ0, bZ0, bZ0};
      f32x4 aI0 = {bI0, bI0, bI0, bI0}, aH0 = {bH0, bH0, bH0, bH0};
      f32x4 aR1 = {bR1, bR1, bR1, bR1}, aZ1 = {bZ1, bZ1, bZ1, bZ1};
      f32x4 aI1 = {bI1, bI1, bI1, bI1}, aH1 = {bH1, bH1, bH1, bH1};
      aR0 = MFMA16(ax, wf[F_IH0(0)], aR0);
      aZ0 = MFMA16(ax, wf[F_IH0(1)], aZ0);
      aI0 = MFMA16(ax, wf[F_IH0(2)], aI0);
#pragma unroll
      for (int kt = 0; kt < 8; ++kt) {  // ah0-dependent (hides ah1 flight)
        aR0 = MFMA16(ah0[kt], wf[F_HH0(0, kt)], aR0);
        aZ0 = MFMA16(ah0[kt], wf[F_HH0(1, kt)], aZ0);
        aH0 = MFMA16(ah0[kt], wf[F_HH0(2, kt)], aH0);
        aR1 = MFMA16(ah0[kt], wf[F_IH1(0, kt)], aR1);
        aZ1 = MFMA16(ah0[kt], wf[F_IH1(1, kt)], aZ1);
        aI1 = MFMA16(ah0[kt], wf[F_IH1(2, kt)], aI1);
      }
      __builtin_amdgcn_sched_barrier(0);
      asm volatile("s_waitcnt vmcnt(0)" ::: "memory");  // ah1 ready
      __builtin_amdgcn_sched_barrier(0);
#pragma unroll
      for (int kt = 0; kt < 8; ++kt) {
        aR1 = MFMA16(ah1[kt], wf[F_HH1(0, kt)], aR1);
        aZ1 = MFMA16(ah1[kt], wf[F_HH1(1, kt)], aZ1);
        aH1 = MFMA16(ah1[kt], wf[F_HH1(2, kt)], aH1);
      }

      if (p < T_) {
        f16* d0 = hb + hfrag(0, p & 1, chunk, s_kt, wv) + s_off;
#pragma unroll
        for (int i = 0; i < 4; ++i) {
          float rr = sigm(aR0[i]);
          float zz = sigm(aZ0[i]);
          float nn = tanh_fast(aI0[i] + rr * aH0[i]);
          h0r[i] = (1.f - zz) * nn + zz * h0r[i];
          sth<F>(d0 + (lgrp * 4 + i) * 8, (f16)h0r[i]);
        }
      }
      if (p > 0) {
        f16* d1 = hb + hfrag(1, (p + 1) & 1, chunk, s_kt, wv) + s_off;
#pragma unroll
        for (int i = 0; i < 4; ++i) {
          float rr = sigm(aR1[i]);
          float zz = sigm(aZ1[i]);
          float nn = tanh_fast(aI1[i] + rr * aH1[i]);
          h1r[i] = (1.f - zz) * nn + zz * h1r[i];
          sth<F>(d1 + (lgrp * 4 + i) * 8, (f16)h1r[i]);
        }
      }
      asm volatile("s_waitcnt vmcnt(0)" ::: "memory");  // data in L2/MALL
      if (lane == 0) stf<F>(fpost, p + 1);
    }
  };
  if (decision == 2) phase_loop(TrueT{});
  else phase_loop(FalseT{});

  // ---- fc head partials ----
  float tmp[4];
#pragma unroll
  for (int i = 0; i < 4; ++i) {
    float v = h1r[i] * fw;
#pragma unroll
    for (int m = 1; m < 16; m <<= 1) v += __shfl_xor(v, m);
    tmp[i] = v;
  }
  if (lrow == 0) {
    float* part = (float*)((char*)ws + PART_B);
#pragma unroll
    for (int i = 0; i < 4; ++i)
      part[(size_t)(rbase + lgrp * 4 + i) * 16 + slice] = tmp[i];
  }
}

__global__ void fc_reduce(const f16* __restrict__ ws,
                          const float* __restrict__ fcb,
                          float* __restrict__ out) {
  int r = blockIdx.x * blockDim.x + threadIdx.x;
  if (r < B_) {
    const float* part = (const float*)((const char*)ws + PART_B);
    float s = fcb[0];
#pragma unroll
    for (int i = 0; i < 16; ++i) s += part[r * 16 + i];
    out[r] = s;
  }
}

extern "C" void kernel_launch(void* const* d_in, const int* in_sizes, int n_in,
                              void* d_out, int out_size, void* d_ws, size_t ws_size,
                              hipStream_t stream) {
  const float* x    = (const float*)d_in[0];
  const float* Wih0 = (const float*)d_in[1];
  const float* Whh0 = (const float*)d_in[2];
  const float* bih0 = (const float*)d_in[3];
  const float* bhh0 = (const float*)d_in[4];
  const float* Wih1 = (const float*)d_in[5];
  const float* Whh1 = (const float*)d_in[6];
  const float* bih1 = (const float*)d_in[7];
  const float* bhh1 = (const float*)d_in[8];
  const float* fcw  = (const float*)d_in[9];
  const float* fcb  = (const float*)d_in[10];

  f16* ws = (f16*)d_ws;  // ~3.4 MB

  init_ws<<<1024, 256, 0, stream>>>(ws);
  prep_weights<<<300, 256, 0, stream>>>(Wih0, Whh0, Wih1, Whh1, ws);
  gru_main<<<256, 256, 0, stream>>>(x, bih0, bhh0, bih1, bhh1, fcw, ws);
  fc_reduce<<<4, 256, 0, stream>>>(ws, fcb, (float*)d_out);
}

// Round 5
// 2096.051 us; speedup vs baseline: 21.0164x; 1.2266x over previous
//
#include <hip/hip_runtime.h>

#define B_ 1024
#define T_ 1024
#define I_ 18
#define H_ 256
#define NCHUNK 16
#define NSLICE 16

typedef _Float16 f16;
typedef _Float16 f16x8 __attribute__((ext_vector_type(8)));
typedef float f32x4 __attribute__((ext_vector_type(4)));

#define MFMA16(a, b, c) __builtin_amdgcn_mfma_f32_16x16x32_f16((a), (b), (c), 0, 0, 0)
#define SB() __builtin_amdgcn_sched_barrier(0)

// ---------------- ws layout ----------------
#define WF_FRAGS 75
#define WF_SLICE (WF_FRAGS * 512)
#define WF_TOTAL (NSLICE * WF_SLICE)             // 1.2 MB (f16)
#define HB0 WF_TOTAL
#define HB_TOTAL (2 * 2 * NCHUNK * 8 * 4 * 512)  // 2 MB (f16)
#define PART_B ((HB0 + HB_TOTAL) * 2)            // partials: 1024x16 f32
#define FLAG_B (PART_B + 1024 * 16 * 4)          // flags: [chunk][wave][32]
#define NFLAGS (NCHUNK * 4 * 32)
#define IDS_B (FLAG_B + NFLAGS * 4)              // 256 xcc ids
#define DEC_B (IDS_B + 256 * 4)                  // decision word
#define F_IH0(g) (g)
#define F_HH0(g, kt) (3 + (g) * 8 + (kt))
#define F_IH1(g, kt) (27 + (g) * 8 + (kt))
#define F_HH1(g, kt) (51 + (g) * 8 + (kt))

struct TrueT { static constexpr bool value = true; };
struct FalseT { static constexpr bool value = false; };

__device__ __forceinline__ int hfrag(int layer, int par, int chunk, int kt, int m) {
  return ((((layer * 2 + par) * NCHUNK + chunk) * 8 + kt) * 4 + m) * 512;
}

__global__ void init_ws(f16* __restrict__ ws) {
  int i = blockIdx.x * blockDim.x + threadIdx.x;
  unsigned* hb = (unsigned*)(ws + HB0);
  for (int k = i; k < HB_TOTAL / 2; k += gridDim.x * blockDim.x) hb[k] = 0u;
  int* flg = (int*)((char*)ws + FLAG_B);
  if (i < NFLAGS + 256 + 1) flg[i] = 0;  // flags + ids + decision
}

__global__ void prep_weights(const float* __restrict__ Wih0,
                             const float* __restrict__ Whh0,
                             const float* __restrict__ Wih1,
                             const float* __restrict__ Whh1,
                             f16* __restrict__ ws) {
  int tid = blockIdx.x * blockDim.x + threadIdx.x;
  if (tid >= NSLICE * WF_FRAGS * 64) return;
  int lane = tid & 63;
  int f = (tid >> 6) % WF_FRAGS;
  int s = tid / (WF_FRAGS * 64);
  int lrow = lane & 15, lgrp = lane >> 4;
  f16 v[8];
  if (f < 3) {  // W_ih0, K=18 zero-padded to 32
    int n = f * H_ + s * 16 + lrow;
#pragma unroll
    for (int j = 0; j < 8; ++j) {
      int k = lgrp * 8 + j;
      v[j] = (k < I_) ? (f16)Wih0[n * I_ + k] : (f16)0.f;
    }
  } else {
    int ff;
    const float* W;
    if (f < 27) { ff = f - 3;  W = Whh0; }
    else if (f < 51) { ff = f - 27; W = Wih1; }
    else { ff = f - 51; W = Whh1; }
    int g = ff >> 3, kt = ff & 7;
    int n = g * H_ + s * 16 + lrow;
    int kb = kt * 32 + lgrp * 8;
#pragma unroll
    for (int j = 0; j < 8; ++j) v[j] = (f16)W[n * H_ + kb + j];
  }
  *(f16x8*)(ws + ((size_t)s * WF_SLICE + f * 512 + lane * 8)) = *(f16x8*)v;
}

__device__ __forceinline__ float sigm(float v) {
  v = fminf(fmaxf(v, -30.f), 30.f);
  return __builtin_amdgcn_rcpf(1.f + __expf(-v));
}
__device__ __forceinline__ float tanh_fast(float v) {
  v = fminf(fmaxf(v, -15.f), 15.f);
  float e = __expf(-2.f * v);
  return (1.f - e) * __builtin_amdgcn_rcpf(1.f + e);
}

// FAST = XCD-local L2 path (plain WT stores, nt loads bypassing stale L1).
template <bool FAST>
__device__ __forceinline__ f16x8 ldh(const f16* p) {
  f16x8 r;
  if (FAST)
    asm volatile("global_load_dwordx4 %0, %1, off nt" : "=&v"(r) : "v"(p));
  else
    asm volatile("global_load_dwordx4 %0, %1, off sc0 sc1" : "=&v"(r) : "v"(p));
  return r;
}
template <bool FAST>
__device__ __forceinline__ void sth(f16* p, f16 v) {
  unsigned u = (unsigned)__builtin_bit_cast(unsigned short, v);
  if (FAST)
    asm volatile("global_store_short %0, %1, off" ::"v"(p), "v"(u) : "memory");
  else
    asm volatile("global_store_short %0, %1, off sc0 sc1" ::"v"(p), "v"(u)
                 : "memory");
}
template <bool FAST>
__device__ __forceinline__ void stf(int* p, int v) {
  if (FAST)
    asm volatile("global_store_dword %0, %1, off" ::"v"(p), "v"(v) : "memory");
  else
    asm volatile("global_store_dword %0, %1, off sc0 sc1" ::"v"(p), "v"(v)
                 : "memory");
}
__device__ __forceinline__ int ld_sys(const int* p) {
  int r;
  asm volatile("global_load_dword %0, %1, off sc0 sc1\n\ts_waitcnt vmcnt(0)"
               : "=&v"(r) : "v"(p) : "memory");
  return r;
}
__device__ __forceinline__ void st_sys(int* p, int v) { stf<false>(p, v); }
__device__ __forceinline__ f32x4 ldx4(const float* p) {  // plain cached load
  f32x4 r;
  asm volatile("global_load_dwordx4 %0, %1, off" : "=&v"(r) : "v"(p));
  return r;
}

// 256 blocks x 256 threads; chunk = blockIdx&15, slice = blockIdx>>4.
__global__ __launch_bounds__(256, 1) void gru_main(
    const float* __restrict__ x, const float* __restrict__ bih0,
    const float* __restrict__ bhh0, const float* __restrict__ bih1,
    const float* __restrict__ bhh1, const float* __restrict__ fcw,
    f16* __restrict__ ws) {
  const int tid = threadIdx.x;
  const int wv = tid >> 6, lane = tid & 63;
  const int lrow = lane & 15, lgrp = lane >> 4;
  const int chunk = blockIdx.x & 15, slice = blockIdx.x >> 4;

  // ---- all 75 weight fragments register/AGPR-resident ----
  f16x8 wf[WF_FRAGS];
  {
    const f16* wb = ws + (size_t)slice * WF_SLICE + lane * 8;
#pragma unroll
    for (int f = 0; f < WF_FRAGS; ++f) wf[f] = *(const f16x8*)(wb + f * 512);
  }

  const int c = slice * 16 + lrow;
  const float bR0 = bih0[c] + bhh0[c], bZ0 = bih0[H_ + c] + bhh0[H_ + c];
  const float bI0 = bih0[2 * H_ + c], bH0 = bhh0[2 * H_ + c];
  const float bR1 = bih1[c] + bhh1[c], bZ1 = bih1[H_ + c] + bhh1[H_ + c];
  const float bI1 = bih1[2 * H_ + c], bH1 = bhh1[2 * H_ + c];
  const float fw = fcw[c];

  float h0r[4] = {0.f, 0.f, 0.f, 0.f}, h1r[4] = {0.f, 0.f, 0.f, 0.f};

  f16* hb = ws + HB0;
  int* flags = (int*)((char*)ws + FLAG_B);
  const int* fpoll = flags + (chunk * 4 + wv) * 32 + (lane & 31);
  int* fpost0 = flags + (chunk * 4 + wv) * 32 + slice;
  int* fpost1 = fpost0 + 16;
  int* ids = (int*)((char*)ws + IDS_B);
  int* dec = (int*)((char*)ws + DEC_B);
  const int rbase = chunk * 64 + wv * 16;
  const float* xrow = x + (size_t)(rbase + lrow) * T_ * I_;
  const int s_kt = slice >> 1;
  const int s_off = 128 * ((slice & 1) * 2 + (lrow >> 3)) + (lrow & 7);
  // x load offsets (f32 idx), clamped in-bounds; junk lanes hit zero weights
  const int o1 = (lgrp == 0) ? 0 : (lgrp == 1) ? 8 : (lgrp == 2) ? 14 : 0;
  const int o2 = (lgrp == 0) ? 4 : (lgrp == 1) ? 12 : 0;
  int dead = 0;

  // ---- runtime XCD-placement verification -> global fast/slow decision ----
  {
    unsigned xcc;
    asm volatile("s_getreg_b32 %0, hwreg(HW_REG_XCC_ID)" : "=s"(xcc));
    if (tid == 0) st_sys(ids + blockIdx.x, (int)xcc + 1);
    if (blockIdx.x == 0 && wv == 0) {
      int ok, guard = 0;
      for (;;) {
        int v0 = ld_sys(ids + lane * 4 + 0), v1 = ld_sys(ids + lane * 4 + 1);
        int v2 = ld_sys(ids + lane * 4 + 2), v3 = ld_sys(ids + lane * 4 + 3);
        ok = (v0 && v1 && v2 && v3);
        if (__all(ok)) { ok = 1; break; }
        if (++guard > (1 << 16)) { ok = 0; break; }
        __builtin_amdgcn_s_sleep(8);
      }
      int verdict = 1;
      if (ok) {
        int eq = 1;
        if (lane < 16) {  // lane = chunk id; blocks of chunk: s*16 + lane
          int r0 = ld_sys(ids + lane);
          for (int s = 1; s < 16; ++s)
            eq &= (ld_sys(ids + s * 16 + lane) == r0);
        }
        verdict = __all(eq) ? 2 : 1;
      }
      if (lane == 0) st_sys(dec, verdict);
    }
  }
  int decision = 1;
  {
    int g = 0;
    for (;;) {
      int d = ld_sys(dec);
      if (d) { decision = d; break; }
      if (++g > (1 << 20)) break;
      __builtin_amdgcn_s_sleep(8);
    }
  }

  auto phase_loop = [&](auto FC) {
    constexpr bool F = decltype(FC)::value;
    // prologue: drain everything, then prefetch x(0)  -> 2 loads in flight
    asm volatile("s_waitcnt vmcnt(0)" ::: "memory");
    SB();
    f32x4 xA1 = ldx4(xrow + o1);
    f32x4 xA2 = ldx4(xrow + o2);

    for (int p = 0; p <= T_; ++p) {
      // ---- poll: flag0[s] >= p (lanes 0-15,32-47), flag1[s] >= p-1 ----
      if (p > 0 && !dead) {
        int tgt = (lane & 16) ? p - 1 : p;
        int guard = 0;
        for (;;) {
          int v;
          if (F)
            asm volatile("global_load_dword %0, %1, off nt"
                         : "=&v"(v) : "v"(fpoll));
          else
            asm volatile("global_load_dword %0, %1, off sc0 sc1"
                         : "=&v"(v) : "v"(fpoll));
          asm volatile("s_waitcnt vmcnt(0)" ::: "memory");
          if (__all(v >= tgt)) break;
          if (++guard > (1 << 18)) { dead = 1; break; }
          __builtin_amdgcn_s_sleep(1);
        }
      }
      SB();
      // ---- issue h loads: ah0 = h0(p-1), ah1 = h1(p-2) ----
      f16x8 ah0[8], ah1[8];
      {
        const f16* b0 = hb + hfrag(0, (p + 1) & 1, chunk, 0, wv) + lane * 8;
        const f16* b1 = hb + hfrag(1, p & 1, chunk, 0, wv) + lane * 8;
#pragma unroll
        for (int kt = 0; kt < 8; ++kt) ah0[kt] = ldh<F>(b0 + kt * 2048);
#pragma unroll
        for (int kt = 0; kt < 8; ++kt) ah1[kt] = ldh<F>(b1 + kt * 2048);
      }
      SB();
      asm volatile("s_waitcnt vmcnt(12)" ::: "memory");  // x + ah0[0..3] done
      SB();
      // ---- ax assemble (x loaded LAST phase; junk lanes hit 0-weights) ----
      f16x8 ax;
      {
        float s0 = (lgrp == 2) ? xA1[2] : xA1[0];
        float s1 = (lgrp == 2) ? xA1[3] : xA1[1];
        ax[0] = (f16)s0;     ax[1] = (f16)s1;
        ax[2] = (f16)xA1[2]; ax[3] = (f16)xA1[3];
        ax[4] = (f16)xA2[0]; ax[5] = (f16)xA2[1];
        ax[6] = (f16)xA2[2]; ax[7] = (f16)xA2[3];
      }
      f32x4 aR0 = {bR0, bR0, bR0, bR0}, aZ0 = {bZ0, bZ0, bZ0, bZ0};
      f32x4 aI0 = {bI0, bI0, bI0, bI0}, aH0 = {bH0, bH0, bH0, bH0};
      f32x4 aR1 = {bR1, bR1, bR1, bR1}, aZ1 = {bZ1, bZ1, bZ1, bZ1};
      f32x4 aI1 = {bI1, bI1, bI1, bI1}, aH1 = {bH1, bH1, bH1, bH1};
#pragma unroll
      for (int kt = 0; kt < 4; ++kt) {  // hh0 on first-half ah0
        aR0 = MFMA16(ah0[kt], wf[F_HH0(0, kt)], aR0);
        aZ0 = MFMA16(ah0[kt], wf[F_HH0(1, kt)], aZ0);
        aH0 = MFMA16(ah0[kt], wf[F_HH0(2, kt)], aH0);
      }
      SB();
      asm volatile("s_waitcnt vmcnt(8)" ::: "memory");  // ah0[4..7] done
      SB();
      aR0 = MFMA16(ax, wf[F_IH0(0)], aR0);
      aZ0 = MFMA16(ax, wf[F_IH0(1)], aZ0);
      aI0 = MFMA16(ax, wf[F_IH0(2)], aI0);
#pragma unroll
      for (int kt = 4; kt < 8; ++kt) {
        aR0 = MFMA16(ah0[kt], wf[F_HH0(0, kt)], aR0);
        aZ0 = MFMA16(ah0[kt], wf[F_HH0(1, kt)], aZ0);
        aH0 = MFMA16(ah0[kt], wf[F_HH0(2, kt)], aH0);
      }
      // ---- h0 update + stores (the inter-wave critical product) ----
      if (p < T_) {
        f16* d0 = hb + hfrag(0, p & 1, chunk, s_kt, wv) + s_off;
#pragma unroll
        for (int i = 0; i < 4; ++i) {
          float rr = sigm(aR0[i]);
          float zz = sigm(aZ0[i]);
          float nn = tanh_fast(aI0[i] + rr * aH0[i]);
          h0r[i] = (1.f - zz) * nn + zz * h0r[i];
          sth<F>(d0 + (lgrp * 4 + i) * 8, (f16)h0r[i]);
        }
      }
      SB();
      asm volatile("s_waitcnt vmcnt(0)" ::: "memory");  // h0 acks + ah1 done
      SB();
      if (p < T_ && lane == 0) stf<F>(fpost0, p + 1);  // EARLY publish
      // ---- layer 1 (off the critical chain, fills others' spin time) ----
#pragma unroll
      for (int kt = 0; kt < 8; ++kt) {
        aR1 = MFMA16(ah0[kt], wf[F_IH1(0, kt)], aR1);
        aZ1 = MFMA16(ah0[kt], wf[F_IH1(1, kt)], aZ1);
        aI1 = MFMA16(ah0[kt], wf[F_IH1(2, kt)], aI1);
        aR1 = MFMA16(ah1[kt], wf[F_HH1(0, kt)], aR1);
        aZ1 = MFMA16(ah1[kt], wf[F_HH1(1, kt)], aZ1);
        aH1 = MFMA16(ah1[kt], wf[F_HH1(2, kt)], aH1);
      }
      if (p > 0) {
        f16* d1 = hb + hfrag(1, (p + 1) & 1, chunk, s_kt, wv) + s_off;
#pragma unroll
        for (int i = 0; i < 4; ++i) {
          float rr = sigm(aR1[i]);
          float zz = sigm(aZ1[i]);
          float nn = tanh_fast(aI1[i] + rr * aH1[i]);
          h1r[i] = (1.f - zz) * nn + zz * h1r[i];
          sth<F>(d1 + (lgrp * 4 + i) * 8, (f16)h1r[i]);
        }
      }
      // ---- x prefetch for next phase (stays in flight across flag1) ----
      {
        int tn = (p + 1 < T_) ? p + 1 : T_ - 1;
        const float* px = xrow + (size_t)tn * I_;
        xA1 = ldx4(px + o1);
        xA2 = ldx4(px + o2);
      }
      SB();
      asm volatile("s_waitcnt vmcnt(2)" ::: "memory");  // h1 acks; x flying
      SB();
      if (p > 0 && lane == 0) stf<F>(fpost1, p);
    }
  };
  if (decision == 2) phase_loop(TrueT{});
  else phase_loop(FalseT{});

  // ---- fc head partials ----
  float tmp[4];
#pragma unroll
  for (int i = 0; i < 4; ++i) {
    float v = h1r[i] * fw;
#pragma unroll
    for (int m = 1; m < 16; m <<= 1) v += __shfl_xor(v, m);
    tmp[i] = v;
  }
  if (lrow == 0) {
    float* part = (float*)((char*)ws + PART_B);
#pragma unroll
    for (int i = 0; i < 4; ++i)
      part[(size_t)(rbase + lgrp * 4 + i) * 16 + slice] = tmp[i];
  }
}

__global__ void fc_reduce(const f16* __restrict__ ws,
                          const float* __restrict__ fcb,
                          float* __restrict__ out) {
  int r = blockIdx.x * blockDim.x + threadIdx.x;
  if (r < B_) {
    const float* part = (const float*)((const char*)ws + PART_B);
    float s = fcb[0];
#pragma unroll
    for (int i = 0; i < 16; ++i) s += part[r * 16 + i];
    out[r] = s;
  }
}

extern "C" void kernel_launch(void* const* d_in, const int* in_sizes, int n_in,
                              void* d_out, int out_size, void* d_ws, size_t ws_size,
                              hipStream_t stream) {
  const float* x    = (const float*)d_in[0];
  const float* Wih0 = (const float*)d_in[1];
  const float* Whh0 = (const float*)d_in[2];
  const float* bih0 = (const float*)d_in[3];
  const float* bhh0 = (const float*)d_in[4];
  const float* Wih1 = (const float*)d_in[5];
  const float* Whh1 = (const float*)d_in[6];
  const float* bih1 = (const float*)d_in[7];
  const float* bhh1 = (const float*)d_in[8];
  const float* fcw  = (const float*)d_in[9];
  const float* fcb  = (const float*)d_in[10];

  f16* ws = (f16*)d_ws;  // ~3.3 MB

  init_ws<<<1024, 256, 0, stream>>>(ws);
  prep_weights<<<300, 256, 0, stream>>>(Wih0, Whh0, Wih1, Whh1, ws);
  gru_main<<<256, 256, 0, stream>>>(x, bih0, bhh0, bih1, bhh1, fcw, ws);
  fc_reduce<<<4, 256, 0, stream>>>(ws, fcb, (float*)d_out);
}

// Round 6
// 2005.088 us; speedup vs baseline: 21.9699x; 1.0454x over previous
//
#include <hip/hip_runtime.h>

#define B_ 1024
#define T_ 1024
#define I_ 18
#define H_ 256
#define NCHUNK 16
#define NSLICE 16

typedef _Float16 f16;
typedef _Float16 f16x8 __attribute__((ext_vector_type(8)));
typedef float f32x4 __attribute__((ext_vector_type(4)));

#define MFMA16(a, b, c) __builtin_amdgcn_mfma_f32_16x16x32_f16((a), (b), (c), 0, 0, 0)
#define SB() __builtin_amdgcn_sched_barrier(0)

// ---------------- sizes (f16 elements) ----------------
#define WF_FRAGS 75
#define WF_SLICE (WF_FRAGS * 512)
#define WF_TOTAL (NSLICE * WF_SLICE)     // 614400 f16
#define H_SLOT (NCHUNK * 8 * 4 * 512)    // 262144 f16 per ring slot (h0 or h1)
#define NFLAGS (NCHUNK * 4 * 32)

struct TrueT { static constexpr bool value = true; };
struct FalseT { static constexpr bool value = false; };

// fragment offset inside a ring slot
__device__ __forceinline__ int hoff(int chunk, int kt, int m) {
  return (((chunk * 8) + kt) * 4 + m) * 512;
}

__global__ void init_ws(f16* __restrict__ hb, int hcount, int* __restrict__ flg) {
  int i = blockIdx.x * blockDim.x + threadIdx.x;
  unsigned* p = (unsigned*)hb;
  for (int k = i; k < hcount / 2; k += gridDim.x * blockDim.x) p[k] = 0u;
  if (i < NFLAGS + 256 + 1) flg[i] = 0;  // flags | ids | dec (contiguous)
}

__global__ void prep_weights(const float* __restrict__ Wih0,
                             const float* __restrict__ Whh0,
                             const float* __restrict__ Wih1,
                             const float* __restrict__ Whh1,
                             f16* __restrict__ ws) {
  int tid = blockIdx.x * blockDim.x + threadIdx.x;
  if (tid >= NSLICE * WF_FRAGS * 64) return;
  int lane = tid & 63;
  int f = (tid >> 6) % WF_FRAGS;
  int s = tid / (WF_FRAGS * 64);
  int lrow = lane & 15, lgrp = lane >> 4;
  f16 v[8];
  if (f < 3) {  // W_ih0, K=18 zero-padded to 32
    int n = f * H_ + s * 16 + lrow;
#pragma unroll
    for (int j = 0; j < 8; ++j) {
      int k = lgrp * 8 + j;
      v[j] = (k < I_) ? (f16)Wih0[n * I_ + k] : (f16)0.f;
    }
  } else {
    int ff;
    const float* W;
    if (f < 27) { ff = f - 3;  W = Whh0; }
    else if (f < 51) { ff = f - 27; W = Wih1; }
    else { ff = f - 51; W = Whh1; }
    int g = ff >> 3, kt = ff & 7;
    int n = g * H_ + s * 16 + lrow;
    int kb = kt * 32 + lgrp * 8;
#pragma unroll
    for (int j = 0; j < 8; ++j) v[j] = (f16)W[n * H_ + kb + j];
  }
  *(f16x8*)(ws + ((size_t)s * WF_SLICE + f * 512 + lane * 8)) = *(f16x8*)v;
}

__device__ __forceinline__ float sigm(float v) {
  // saturates correctly via inf propagation: exp(inf)->inf, rcp(inf)->0
  return __builtin_amdgcn_rcpf(1.f + __expf(-v));
}
__device__ __forceinline__ float tanh_fast(float v) {
  v = fmaxf(v, -15.f);  // only guard: exp overflow -> NaN on the negative side
  float e = __expf(-2.f * v);
  return (1.f - e) * __builtin_amdgcn_rcpf(1.f + e);
}

// FAST = XCD-local L2 path (plain WT stores, nt loads bypassing stale L1).
template <bool FAST>
__device__ __forceinline__ f16x8 ldh(const f16* p) {
  f16x8 r;
  if (FAST)
    asm volatile("global_load_dwordx4 %0, %1, off nt" : "=&v"(r) : "v"(p));
  else
    asm volatile("global_load_dwordx4 %0, %1, off sc0 sc1" : "=&v"(r) : "v"(p));
  return r;
}
template <bool FAST>
__device__ __forceinline__ void sth(f16* p, f16 v) {
  unsigned u = (unsigned)__builtin_bit_cast(unsigned short, v);
  if (FAST)
    asm volatile("global_store_short %0, %1, off" ::"v"(p), "v"(u) : "memory");
  else
    asm volatile("global_store_short %0, %1, off sc0 sc1" ::"v"(p), "v"(u)
                 : "memory");
}
template <bool FAST>
__device__ __forceinline__ void stf(int* p, int v) {
  if (FAST)
    asm volatile("global_store_dword %0, %1, off" ::"v"(p), "v"(v) : "memory");
  else
    asm volatile("global_store_dword %0, %1, off sc0 sc1" ::"v"(p), "v"(v)
                 : "memory");
}
__device__ __forceinline__ int ld_sys(const int* p) {
  int r;
  asm volatile("global_load_dword %0, %1, off sc0 sc1\n\ts_waitcnt vmcnt(0)"
               : "=&v"(r) : "v"(p) : "memory");
  return r;
}
__device__ __forceinline__ void st_sys(int* p, int v) { stf<false>(p, v); }
__device__ __forceinline__ f32x4 ldx4(const float* p) {
  f32x4 r;
  asm volatile("global_load_dwordx4 %0, %1, off" : "=&v"(r) : "v"(p));
  return r;
}

// 256 blocks x 512 threads (8 waves, 2/SIMD).
// chunk = blockIdx&15, slice = blockIdx>>4.
// waves 0-3: layer-0 recurrence (critical).  waves 4-7: layer-1 (trails 1 phase).
__global__ __launch_bounds__(512, 2) void gru_main(
    const float* __restrict__ x, const float* __restrict__ bih0,
    const float* __restrict__ bhh0, const float* __restrict__ bih1,
    const float* __restrict__ bhh1, const float* __restrict__ fcw,
    const f16* __restrict__ wfr, f16* __restrict__ hb0, f16* __restrict__ hb1,
    float* __restrict__ part, int* __restrict__ flags, int* __restrict__ ids,
    int* __restrict__ dec, int hmask) {
  __shared__ f16 whh1_l[24 * 512];  // 24KB: W_hh1 slice fragments (L1 B-operand)

  const int tid = threadIdx.x;
  const int wv = tid >> 6, lane = tid & 63;
  const int w = wv & 3;  // row-group / SIMD id
  const bool isL0 = wv < 4;
  const int lrow = lane & 15, lgrp = lane >> 4;
  const int chunk = blockIdx.x & 15, slice = blockIdx.x >> 4;

  // cooperative LDS fill: hh1 fragments (frag ids 51..74)
  for (int i = tid; i < 24 * 64; i += 512)
    ((f16x8*)whh1_l)[i] =
        ((const f16x8*)(wfr + (size_t)slice * WF_SLICE + 51 * 512))[i];

  const int c = slice * 16 + lrow;
  const int* fpoll = flags + (chunk * 4 + w) * 32 + (lane & 31);
  const int rbase = chunk * 64 + w * 16;
  const int s_kt = slice >> 1;
  const int s_off = 128 * ((slice & 1) * 2 + (lrow >> 3)) + (lrow & 7);

  // ---- runtime XCD-placement verification -> global fast/slow decision ----
  {
    unsigned xcc;
    asm volatile("s_getreg_b32 %0, hwreg(HW_REG_XCC_ID)" : "=s"(xcc));
    if (tid == 0) st_sys(ids + blockIdx.x, (int)xcc + 1);
    if (blockIdx.x == 0 && wv == 0) {
      int ok, guard = 0;
      for (;;) {
        int v0 = ld_sys(ids + lane * 4 + 0), v1 = ld_sys(ids + lane * 4 + 1);
        int v2 = ld_sys(ids + lane * 4 + 2), v3 = ld_sys(ids + lane * 4 + 3);
        ok = (v0 && v1 && v2 && v3);
        if (__all(ok)) { ok = 1; break; }
        if (++guard > (1 << 16)) { ok = 0; break; }
        __builtin_amdgcn_s_sleep(8);
      }
      int verdict = 1;
      if (ok) {
        int eq = 1;
        if (lane < 16) {  // lane = chunk id; blocks of chunk: s*16 + lane
          int r0 = ld_sys(ids + lane);
          for (int s = 1; s < 16; ++s)
            eq &= (ld_sys(ids + s * 16 + lane) == r0);
        }
        verdict = __all(eq) ? 2 : 1;
      }
      if (lane == 0) st_sys(dec, verdict);
    }
  }
  int decision = 1;
  {
    int g = 0;
    for (;;) {
      int d = ld_sys(dec);
      if (d) { decision = d; break; }
      if (++g > (1 << 20)) break;
      __builtin_amdgcn_s_sleep(8);
    }
  }
  __syncthreads();  // LDS ready; only block-wide barrier

  if (isL0) {
    // =========================== LAYER-0 WAVES ===========================
    f16x8 wfA[27];  // ih0(3) + hh0(24)
    {
      const f16* wb = wfr + (size_t)slice * WF_SLICE + lane * 8;
#pragma unroll
      for (int f = 0; f < 27; ++f) wfA[f] = *(const f16x8*)(wb + f * 512);
    }
    const float bR0 = bih0[c] + bhh0[c], bZ0 = bih0[H_ + c] + bhh0[H_ + c];
    const float bI0 = bih0[2 * H_ + c], bH0 = bhh0[2 * H_ + c];
    float h0r[4] = {0.f, 0.f, 0.f, 0.f};
    int* fpost0 = flags + (chunk * 4 + w) * 32 + slice;
    const float* xrow = x + (size_t)(rbase + lrow) * T_ * I_;
    const int o1 = (lgrp == 0) ? 0 : (lgrp == 1) ? 8 : (lgrp == 2) ? 14 : 0;
    const int o2 = (lgrp == 0) ? 4 : (lgrp == 1) ? 12 : 0;
    int dead = 0;

    auto loop0 = [&](auto FC) {
      constexpr bool F = decltype(FC)::value;
      asm volatile("s_waitcnt vmcnt(0)" ::: "memory");
      SB();
      f32x4 xA1 = ldx4(xrow + o1);
      f32x4 xA2 = ldx4(xrow + o2);
      for (int p = 0; p < T_; ++p) {
        if (p > 0 && !dead) {
          // flag0 >= p (h0(p-1) ready), flag1 >= p-hmask (ring safety)
          int tgt = (lane & 16) ? (p - hmask) : p;
          int guard = 0;
          for (;;) {
            int v;
            if (F)
              asm volatile("global_load_dword %0, %1, off nt"
                           : "=&v"(v) : "v"(fpoll));
            else
              asm volatile("global_load_dword %0, %1, off sc0 sc1"
                           : "=&v"(v) : "v"(fpoll));
            asm volatile("s_waitcnt vmcnt(0)" ::: "memory");
            if (__all(v >= tgt)) break;
            if (++guard > (1 << 18)) { dead = 1; break; }
          }
        }
        SB();
        __builtin_amdgcn_s_setprio(1);
        f16x8 ah0[8];
        {
          const f16* b0 = hb0 + (size_t)((p - 1) & hmask) * H_SLOT +
                          hoff(chunk, 0, w) + lane * 8;
#pragma unroll
          for (int kt = 0; kt < 8; ++kt) ah0[kt] = ldh<F>(b0 + kt * 2048);
        }
        SB();
        asm volatile("s_waitcnt vmcnt(4)" ::: "memory");  // x + ah0[0..3]
        SB();
        f16x8 ax;
        {
          float s0 = (lgrp == 2) ? xA1[2] : xA1[0];
          float s1 = (lgrp == 2) ? xA1[3] : xA1[1];
          ax[0] = (f16)s0;     ax[1] = (f16)s1;
          ax[2] = (f16)xA1[2]; ax[3] = (f16)xA1[3];
          ax[4] = (f16)xA2[0]; ax[5] = (f16)xA2[1];
          ax[6] = (f16)xA2[2]; ax[7] = (f16)xA2[3];
        }
        f32x4 aR = {bR0, bR0, bR0, bR0}, aZ = {bZ0, bZ0, bZ0, bZ0};
        f32x4 aI = {bI0, bI0, bI0, bI0}, aH = {bH0, bH0, bH0, bH0};
        aR = MFMA16(ax, wfA[0], aR);
        aZ = MFMA16(ax, wfA[1], aZ);
        aI = MFMA16(ax, wfA[2], aI);
#pragma unroll
        for (int kt = 0; kt < 4; ++kt) {
          aR = MFMA16(ah0[kt], wfA[3 + kt], aR);
          aZ = MFMA16(ah0[kt], wfA[11 + kt], aZ);
          aH = MFMA16(ah0[kt], wfA[19 + kt], aH);
        }
        SB();
        asm volatile("s_waitcnt vmcnt(0)" ::: "memory");  // ah0[4..7]
        SB();
#pragma unroll
        for (int kt = 4; kt < 8; ++kt) {
          aR = MFMA16(ah0[kt], wfA[3 + kt], aR);
          aZ = MFMA16(ah0[kt], wfA[11 + kt], aZ);
          aH = MFMA16(ah0[kt], wfA[19 + kt], aH);
        }
        {
          f16* d0 = hb0 + (size_t)(p & hmask) * H_SLOT +
                    hoff(chunk, s_kt, w) + s_off;
#pragma unroll
          for (int i = 0; i < 4; ++i) {
            float rr = sigm(aR[i]);
            float zz = sigm(aZ[i]);
            float nn = tanh_fast(aI[i] + rr * aH[i]);
            h0r[i] = (1.f - zz) * nn + zz * h0r[i];
            sth<F>(d0 + (lgrp * 4 + i) * 8, (f16)h0r[i]);
          }
        }
        SB();
        asm volatile("s_waitcnt vmcnt(0)" ::: "memory");  // store acks
        SB();
        if (lane == 0) stf<F>(fpost0, p + 1);
        __builtin_amdgcn_s_setprio(0);
        {  // x prefetch for next phase (in flight across the poll)
          int tn = (p + 1 < T_) ? p + 1 : T_ - 1;
          const float* px = xrow + (size_t)tn * I_;
          xA1 = ldx4(px + o1);
          xA2 = ldx4(px + o2);
        }
      }
    };
    if (decision == 2) loop0(TrueT{});
    else loop0(FalseT{});
  } else {
    // =========================== LAYER-1 WAVES ===========================
    f16x8 wfB[24];  // ih1
    {
      const f16* wb = wfr + (size_t)slice * WF_SLICE + 27 * 512 + lane * 8;
#pragma unroll
      for (int f = 0; f < 24; ++f) wfB[f] = *(const f16x8*)(wb + f * 512);
    }
    const float bR1 = bih1[c] + bhh1[c], bZ1 = bih1[H_ + c] + bhh1[H_ + c];
    const float bI1 = bih1[2 * H_ + c], bH1 = bhh1[2 * H_ + c];
    const float fw = fcw[c];
    float h1r[4] = {0.f, 0.f, 0.f, 0.f};
    int* fpost1 = flags + (chunk * 4 + w) * 32 + 16 + slice;
    int dead = 0;

    auto loop1 = [&](auto FC) {
      constexpr bool F = decltype(FC)::value;
      for (int p = 1; p <= T_; ++p) {
        if (!dead) {
          // flag0 >= p (h0(p-1) ready), flag1 >= p-1 (h1(p-2) ready)
          int tgt = (lane & 16) ? (p - 1) : p;
          int guard = 0;
          for (;;) {
            int v;
            if (F)
              asm volatile("global_load_dword %0, %1, off nt"
                           : "=&v"(v) : "v"(fpoll));
            else
              asm volatile("global_load_dword %0, %1, off sc0 sc1"
                           : "=&v"(v) : "v"(fpoll));
            asm volatile("s_waitcnt vmcnt(0)" ::: "memory");
            if (__all(v >= tgt)) break;
            if (++guard > (1 << 18)) { dead = 1; break; }
          }
        }
        SB();
        f16x8 ah0[8], ah1[8];
        {
          const f16* b0 = hb0 + (size_t)((p - 1) & hmask) * H_SLOT +
                          hoff(chunk, 0, w) + lane * 8;
          const f16* b1 = hb1 + (size_t)(p & 1) * H_SLOT +
                          hoff(chunk, 0, w) + lane * 8;
#pragma unroll
          for (int kt = 0; kt < 8; ++kt) ah0[kt] = ldh<F>(b0 + kt * 2048);
#pragma unroll
          for (int kt = 0; kt < 8; ++kt) ah1[kt] = ldh<F>(b1 + kt * 2048);
        }
        SB();
        asm volatile("s_waitcnt vmcnt(8)" ::: "memory");  // ah0 done
        SB();
        f32x4 aR = {bR1, bR1, bR1, bR1}, aZ = {bZ1, bZ1, bZ1, bZ1};
        f32x4 aI = {bI1, bI1, bI1, bI1}, aH = {bH1, bH1, bH1, bH1};
#pragma unroll
        for (int kt = 0; kt < 8; ++kt) {  // ih1 (reg weights) on ah0
          aR = MFMA16(ah0[kt], wfB[kt], aR);
          aZ = MFMA16(ah0[kt], wfB[8 + kt], aZ);
          aI = MFMA16(ah0[kt], wfB[16 + kt], aI);
        }
        SB();
        asm volatile("s_waitcnt vmcnt(0)" ::: "memory");  // ah1 done
        SB();
#pragma unroll
        for (int kt = 0; kt < 8; ++kt) {  // hh1 (LDS weights) on ah1
          f16x8 br = *(const f16x8*)&whh1_l[(0 * 8 + kt) * 512 + lane * 8];
          f16x8 bz = *(const f16x8*)&whh1_l[(1 * 8 + kt) * 512 + lane * 8];
          f16x8 bn = *(const f16x8*)&whh1_l[(2 * 8 + kt) * 512 + lane * 8];
          aR = MFMA16(ah1[kt], br, aR);
          aZ = MFMA16(ah1[kt], bz, aZ);
          aH = MFMA16(ah1[kt], bn, aH);
        }
        {
          f16* d1 = hb1 + (size_t)((p - 1) & 1) * H_SLOT +
                    hoff(chunk, s_kt, w) + s_off;
#pragma unroll
          for (int i = 0; i < 4; ++i) {
            float rr = sigm(aR[i]);
            float zz = sigm(aZ[i]);
            float nn = tanh_fast(aI[i] + rr * aH[i]);
            h1r[i] = (1.f - zz) * nn + zz * h1r[i];
            sth<F>(d1 + (lgrp * 4 + i) * 8, (f16)h1r[i]);
          }
        }
        SB();
        asm volatile("s_waitcnt vmcnt(0)" ::: "memory");  // store acks
        SB();
        if (lane == 0) stf<F>(fpost1, p);
      }
    };
    if (decision == 2) loop1(TrueT{});
    else loop1(FalseT{});

    // ---- fc head partials (L1 waves own final h1) ----
    float tmp[4];
#pragma unroll
    for (int i = 0; i < 4; ++i) {
      float v = h1r[i] * fw;
#pragma unroll
      for (int m = 1; m < 16; m <<= 1) v += __shfl_xor(v, m);
      tmp[i] = v;
    }
    if (lrow == 0) {
#pragma unroll
      for (int i = 0; i < 4; ++i)
        part[(size_t)(rbase + lgrp * 4 + i) * 16 + slice] = tmp[i];
    }
  }
}

__global__ void fc_reduce(const float* __restrict__ part,
                          const float* __restrict__ fcb,
                          float* __restrict__ out) {
  int r = blockIdx.x * blockDim.x + threadIdx.x;
  if (r < B_) {
    float s = fcb[0];
#pragma unroll
    for (int i = 0; i < 16; ++i) s += part[r * 16 + i];
    out[r] = s;
  }
}

extern "C" void kernel_launch(void* const* d_in, const int* in_sizes, int n_in,
                              void* d_out, int out_size, void* d_ws, size_t ws_size,
                              hipStream_t stream) {
  const float* x    = (const float*)d_in[0];
  const float* Wih0 = (const float*)d_in[1];
  const float* Whh0 = (const float*)d_in[2];
  const float* bih0 = (const float*)d_in[3];
  const float* bhh0 = (const float*)d_in[4];
  const float* Wih1 = (const float*)d_in[5];
  const float* Whh1 = (const float*)d_in[6];
  const float* bih1 = (const float*)d_in[7];
  const float* bhh1 = (const float*)d_in[8];
  const float* fcw  = (const float*)d_in[9];
  const float* fcb  = (const float*)d_in[10];

  // ws carve-up (host-side arithmetic only)
  size_t tail = 1024 * 16 * 4 + (NFLAGS + 256 + 8) * 4;
  size_t need4 = (size_t)(WF_TOTAL + 6 * H_SLOT) * 2 + tail;  // ring-4 h0
  int hmask = (ws_size >= need4) ? 3 : 1;  // ring-2 fallback (R5 footprint)
  f16* wfr = (f16*)d_ws;
  f16* hb0 = wfr + WF_TOTAL;
  f16* hb1 = hb0 + (size_t)(hmask + 1) * H_SLOT;
  float* part = (float*)(hb1 + 2 * H_SLOT);
  int* flags = (int*)(part + 1024 * 16);
  int* ids = flags + NFLAGS;
  int* dec = ids + 256;
  int hcount = (hmask + 3) * H_SLOT;  // hb0 + hb1 contiguous zero region

  init_ws<<<1024, 256, 0, stream>>>(hb0, hcount, flags);
  prep_weights<<<300, 256, 0, stream>>>(Wih0, Whh0, Wih1, Whh1, wfr);
  gru_main<<<256, 512, 0, stream>>>(x, bih0, bhh0, bih1, bhh1, fcw, wfr, hb0,
                                    hb1, part, flags, ids, dec, hmask);
  fc_reduce<<<4, 256, 0, stream>>>(part, fcb, (float*)d_out);
}

// Round 7
// 1905.122 us; speedup vs baseline: 23.1227x; 1.0525x over previous
//
#include <hip/hip_runtime.h>

#define B_ 1024
#define T_ 1024
#define I_ 18
#define H_ 256
#define NCHUNK 16
#define NSLICE 16

typedef _Float16 f16;
typedef _Float16 f16x8 __attribute__((ext_vector_type(8)));
typedef float f32x4 __attribute__((ext_vector_type(4)));

#define MFMA16(a, b, c) __builtin_amdgcn_mfma_f32_16x16x32_f16((a), (b), (c), 0, 0, 0)
#define SB() __builtin_amdgcn_sched_barrier(0)

// ---------------- ws layout (no weight staging anymore) ----------------
#define H_SLOT (NCHUNK * 8 * 4 * 512)  // 262144 f16 = 512KB per ring slot
#define NFLAGS (NCHUNK * 4 * 32)
// ws: hb0[4 slots] | hb1[2 slots] | part(1024x16 f32) | flags | ids | dec

struct TrueT { static constexpr bool value = true; };
struct FalseT { static constexpr bool value = false; };

__device__ __forceinline__ int hoff(int chunk, int kt, int m) {
  return (((chunk * 8) + kt) * 4 + m) * 512;
}

__global__ void init_ws(f16* __restrict__ hb, int* __restrict__ flg) {
  int i = blockIdx.x * blockDim.x + threadIdx.x;
  unsigned* p = (unsigned*)hb;
  for (int k = i; k < 3 * H_SLOT; k += gridDim.x * blockDim.x) p[k] = 0u;
  if (i < NFLAGS + 256 + 1) flg[i] = 0;  // flags | ids | dec (contiguous)
}

__device__ __forceinline__ float sigm(float v) {
  return __builtin_amdgcn_rcpf(1.f + __expf(-v));
}
__device__ __forceinline__ float tanh_fast(float v) {
  v = fmaxf(v, -15.f);
  float e = __expf(-2.f * v);
  return (1.f - e) * __builtin_amdgcn_rcpf(1.f + e);
}
// load 8 consecutive f32 -> f16x8 (16B-aligned source)
__device__ __forceinline__ f16x8 cvt8(const float* q) {
  const f32x4* a = (const f32x4*)q;
  f32x4 u = a[0], v = a[1];
  f16x8 r;
  r[0] = (f16)u[0]; r[1] = (f16)u[1]; r[2] = (f16)u[2]; r[3] = (f16)u[3];
  r[4] = (f16)v[0]; r[5] = (f16)v[1]; r[6] = (f16)v[2]; r[7] = (f16)v[3];
  return r;
}

// FAST = XCD-local L2 path (plain WT stores, nt loads bypassing stale L1).
template <bool FAST>
__device__ __forceinline__ f16x8 ldh(const f16* p) {
  f16x8 r;
  if (FAST)
    asm volatile("global_load_dwordx4 %0, %1, off nt" : "=&v"(r) : "v"(p));
  else
    asm volatile("global_load_dwordx4 %0, %1, off sc0 sc1" : "=&v"(r) : "v"(p));
  return r;
}
template <bool FAST>
__device__ __forceinline__ void sth(f16* p, f16 v) {
  unsigned u = (unsigned)__builtin_bit_cast(unsigned short, v);
  if (FAST)
    asm volatile("global_store_short %0, %1, off" ::"v"(p), "v"(u) : "memory");
  else
    asm volatile("global_store_short %0, %1, off sc0 sc1" ::"v"(p), "v"(u)
                 : "memory");
}
template <bool FAST>
__device__ __forceinline__ void stf(int* p, int v) {
  if (FAST)
    asm volatile("global_store_dword %0, %1, off" ::"v"(p), "v"(v) : "memory");
  else
    asm volatile("global_store_dword %0, %1, off sc0 sc1" ::"v"(p), "v"(v)
                 : "memory");
}
template <bool FAST>
__device__ __forceinline__ int ldf(const int* p) {  // flag load + drain
  int r;
  if (FAST)
    asm volatile("global_load_dword %0, %1, off nt\n\ts_waitcnt vmcnt(0)"
                 : "=&v"(r) : "v"(p) : "memory");
  else
    asm volatile("global_load_dword %0, %1, off sc0 sc1\n\ts_waitcnt vmcnt(0)"
                 : "=&v"(r) : "v"(p) : "memory");
  return r;
}
__device__ __forceinline__ int ld_sys(const int* p) {
  int r;
  asm volatile("global_load_dword %0, %1, off sc0 sc1\n\ts_waitcnt vmcnt(0)"
               : "=&v"(r) : "v"(p) : "memory");
  return r;
}
__device__ __forceinline__ void st_sys(int* p, int v) { stf<false>(p, v); }
__device__ __forceinline__ f32x4 ldx4(const float* p) {
  f32x4 r;
  asm volatile("global_load_dwordx4 %0, %1, off" : "=&v"(r) : "v"(p));
  return r;
}

// 256 blocks x 512 threads; chunk = blockIdx&15, slice = blockIdx>>4.
// waves 0-3: layer-0 recurrence (critical). waves 4-7: layer-1 (trails 1 phase).
// h0 ring-4, h1 ring-2 (unconditional; weights gathered in-kernel, not staged).
__global__ __launch_bounds__(512, 2) void gru_main(
    const float* __restrict__ x, const float* __restrict__ Wih0,
    const float* __restrict__ Whh0, const float* __restrict__ Wih1,
    const float* __restrict__ Whh1, const float* __restrict__ bih0,
    const float* __restrict__ bhh0, const float* __restrict__ bih1,
    const float* __restrict__ bhh1, const float* __restrict__ fcw,
    f16* __restrict__ hb0, f16* __restrict__ hb1, float* __restrict__ part,
    int* __restrict__ flags, int* __restrict__ ids, int* __restrict__ dec) {
  __shared__ f16 whh1_l[24 * 512];  // 24KB: W_hh1 slice fragments (L1 B-operand)

  const int tid = threadIdx.x;
  const int wv = tid >> 6, lane = tid & 63;
  const int w = wv & 3;
  const bool isL0 = wv < 4;
  const int lrow = lane & 15, lgrp = lane >> 4;
  const int chunk = blockIdx.x & 15, slice = blockIdx.x >> 4;
  const int c = slice * 16 + lrow;

  // cooperative LDS fill of hh1 fragments, straight from fp32 W_hh1
  for (int idx = tid; idx < 24 * 64; idx += 512) {
    int f = idx >> 6, l = idx & 63;
    int g = f >> 3, kt = f & 7;
    int n = g * H_ + slice * 16 + (l & 15);
    ((f16x8*)whh1_l)[idx] = cvt8(&Whh1[n * H_ + kt * 32 + (l >> 4) * 8]);
  }

  const int* fpoll = flags + (chunk * 4 + w) * 32 + (lane & 31);
  const int rbase = chunk * 64 + w * 16;
  const int s_kt = slice >> 1;
  const int s_off = 128 * ((slice & 1) * 2 + (lrow >> 3)) + (lrow & 7);

  // ---- runtime XCD-placement verification -> global fast/slow decision ----
  {
    unsigned xcc;
    asm volatile("s_getreg_b32 %0, hwreg(HW_REG_XCC_ID)" : "=s"(xcc));
    if (tid == 0) st_sys(ids + blockIdx.x, (int)xcc + 1);
    if (blockIdx.x == 0 && wv == 0) {
      int ok, guard = 0;
      for (;;) {
        int v0 = ld_sys(ids + lane * 4 + 0), v1 = ld_sys(ids + lane * 4 + 1);
        int v2 = ld_sys(ids + lane * 4 + 2), v3 = ld_sys(ids + lane * 4 + 3);
        ok = (v0 && v1 && v2 && v3);
        if (__all(ok)) { ok = 1; break; }
        if (++guard > (1 << 16)) { ok = 0; break; }
        __builtin_amdgcn_s_sleep(8);
      }
      int verdict = 1;
      if (ok) {
        int eq = 1;
        if (lane < 16) {
          int r0 = ld_sys(ids + lane);
          for (int s = 1; s < 16; ++s)
            eq &= (ld_sys(ids + s * 16 + lane) == r0);
        }
        verdict = __all(eq) ? 2 : 1;
      }
      if (lane == 0) st_sys(dec, verdict);
    }
  }
  int decision = 1;
  {
    int g = 0;
    for (;;) {
      int d = ld_sys(dec);
      if (d) { decision = d; break; }
      if (++g > (1 << 20)) break;
      __builtin_amdgcn_s_sleep(8);
    }
  }
  __syncthreads();  // LDS ready; only block-wide barrier

  if (isL0) {
    // =========================== LAYER-0 WAVES ===========================
    f16x8 wfA[27];  // ih0(3) + hh0(24) gathered from fp32 weights
#pragma unroll
    for (int g = 0; g < 3; ++g) {
      int n = g * H_ + c;
      f16 v[8];
#pragma unroll
      for (int j = 0; j < 8; ++j) {
        int k = lgrp * 8 + j;
        v[j] = (k < I_) ? (f16)Wih0[n * I_ + k] : (f16)0.f;
      }
      wfA[g] = *(f16x8*)v;
    }
#pragma unroll
    for (int g = 0; g < 3; ++g)
#pragma unroll
      for (int kt = 0; kt < 8; ++kt)
        wfA[3 + g * 8 + kt] =
            cvt8(&Whh0[(g * H_ + c) * H_ + kt * 32 + lgrp * 8]);

    const float bR0 = bih0[c] + bhh0[c], bZ0 = bih0[H_ + c] + bhh0[H_ + c];
    const float bI0 = bih0[2 * H_ + c], bH0 = bhh0[2 * H_ + c];
    float h0r[4] = {0.f, 0.f, 0.f, 0.f};
    int* fpost0 = flags + (chunk * 4 + w) * 32 + slice;
    const float* xrow = x + (size_t)(rbase + lrow) * T_ * I_;
    const int o1 = (lgrp == 0) ? 0 : (lgrp == 1) ? 8 : (lgrp == 2) ? 14 : 0;
    const int o2 = (lgrp == 0) ? 4 : (lgrp == 1) ? 12 : 0;
    int dead = 0;

    auto loop0 = [&](auto FC) {
      constexpr bool F = decltype(FC)::value;
      asm volatile("s_waitcnt vmcnt(0)" ::: "memory");
      SB();
      f32x4 xA1 = ldx4(xrow + o1);
      f32x4 xA2 = ldx4(xrow + o2);
      asm volatile("s_waitcnt vmcnt(0)" ::: "memory");  // x(0) home
      SB();
      for (int p = 0; p < T_; ++p) {
        __builtin_amdgcn_s_setprio(1);
        if (p > 0 && !dead) {
          // flag0 >= p (h0(p-1) ready); flag1 >= p-3 (ring-4 safety).
          // First iter's vmcnt(0) also absorbs the x(p) prefetch tail.
          int guard = 0;
          for (;;) {
            int v = ldf<F>(fpoll);
            int tgt = (lane & 16) ? (p - 3) : p;
            if (__all(v >= tgt)) break;
            if (++guard > (1 << 18)) { dead = 1; break; }
          }
        }
        SB();
        f16x8 ah0[8];
        {
          const f16* b0 = hb0 + (size_t)((p - 1) & 3) * H_SLOT +
                          hoff(chunk, 0, w) + lane * 8;
#pragma unroll
          for (int kt = 0; kt < 8; ++kt) ah0[kt] = ldh<F>(b0 + kt * 2048);
        }
        SB();
        // ax assemble + ih0 MFMAs: x-only deps, overlap ah0 flight
        f16x8 ax;
        {
          float s0 = (lgrp == 2) ? xA1[2] : xA1[0];
          float s1 = (lgrp == 2) ? xA1[3] : xA1[1];
          ax[0] = (f16)s0;     ax[1] = (f16)s1;
          ax[2] = (f16)xA1[2]; ax[3] = (f16)xA1[3];
          ax[4] = (f16)xA2[0]; ax[5] = (f16)xA2[1];
          ax[6] = (f16)xA2[2]; ax[7] = (f16)xA2[3];
        }
        f32x4 aR = {bR0, bR0, bR0, bR0}, aZ = {bZ0, bZ0, bZ0, bZ0};
        f32x4 aI = {bI0, bI0, bI0, bI0}, aH = {bH0, bH0, bH0, bH0};
        aR = MFMA16(ax, wfA[0], aR);
        aZ = MFMA16(ax, wfA[1], aZ);
        aI = MFMA16(ax, wfA[2], aI);
        SB();
        asm volatile("s_waitcnt vmcnt(4)" ::: "memory");  // ah0[0..3]
        SB();
#pragma unroll
        for (int kt = 0; kt < 4; ++kt) {
          aR = MFMA16(ah0[kt], wfA[3 + kt], aR);
          aZ = MFMA16(ah0[kt], wfA[11 + kt], aZ);
          aH = MFMA16(ah0[kt], wfA[19 + kt], aH);
        }
        SB();
        asm volatile("s_waitcnt vmcnt(0)" ::: "memory");  // ah0[4..7]
        SB();
#pragma unroll
        for (int kt = 4; kt < 8; ++kt) {
          aR = MFMA16(ah0[kt], wfA[3 + kt], aR);
          aZ = MFMA16(ah0[kt], wfA[11 + kt], aZ);
          aH = MFMA16(ah0[kt], wfA[19 + kt], aH);
        }
        {
          f16* d0 = hb0 + (size_t)(p & 3) * H_SLOT + hoff(chunk, s_kt, w) +
                    s_off;
#pragma unroll
          for (int i = 0; i < 4; ++i) {
            float rr = sigm(aR[i]);
            float zz = sigm(aZ[i]);
            float nn = tanh_fast(aI[i] + rr * aH[i]);
            h0r[i] = (1.f - zz) * nn + zz * h0r[i];
            sth<F>(d0 + (lgrp * 4 + i) * 8, (f16)h0r[i]);
          }
        }
        // x prefetch AFTER stores: stores retire first (in-order) ->
        // counted vmcnt(2) acks stores while x stays in flight.
        {
          int tn = (p + 1 < T_) ? p + 1 : T_ - 1;
          const float* px = xrow + (size_t)tn * I_;
          xA1 = ldx4(px + o1);
          xA2 = ldx4(px + o2);
        }
        SB();
        asm volatile("s_waitcnt vmcnt(2)" ::: "memory");  // h0 acks; x flying
        SB();
        if (lane == 0) stf<F>(fpost0, p + 1);
        __builtin_amdgcn_s_setprio(0);
      }
    };
    if (decision == 2) loop0(TrueT{});
    else loop0(FalseT{});
  } else {
    // =========================== LAYER-1 WAVES ===========================
    f16x8 wfB[24];  // ih1 gathered from fp32 weights
#pragma unroll
    for (int g = 0; g < 3; ++g)
#pragma unroll
      for (int kt = 0; kt < 8; ++kt)
        wfB[g * 8 + kt] =
            cvt8(&Wih1[(g * H_ + c) * H_ + kt * 32 + lgrp * 8]);

    const float bR1 = bih1[c] + bhh1[c], bZ1 = bih1[H_ + c] + bhh1[H_ + c];
    const float bI1 = bih1[2 * H_ + c], bH1 = bhh1[2 * H_ + c];
    const float fw = fcw[c];
    float h1r[4] = {0.f, 0.f, 0.f, 0.f};
    int* fpost1 = flags + (chunk * 4 + w) * 32 + 16 + slice;
    int dead = 0;

    auto loop1 = [&](auto FC) {
      constexpr bool F = decltype(FC)::value;
      for (int p = 1; p <= T_; ++p) {
        // stage A: flag1 >= p-1 (h1(p-2) ready) -- usually already true
        if (!dead) {
          int guard = 0;
          for (;;) {
            int v = ldf<F>(fpoll);
            if (__all((lane & 16) ? (v >= p - 1) : 1)) break;
            if (++guard > (1 << 18)) { dead = 1; break; }
          }
        }
        SB();
        f16x8 ah1[8];
        {
          const f16* b1 = hb1 + (size_t)(p & 1) * H_SLOT +
                          hoff(chunk, 0, w) + lane * 8;
#pragma unroll
          for (int kt = 0; kt < 8; ++kt) ah1[kt] = ldh<F>(b1 + kt * 2048);
        }
        SB();
        // stage B: flag0 >= p; its vmcnt(0) drains ah1 under the flag wait
        if (!dead) {
          int guard = 0;
          for (;;) {
            int v = ldf<F>(fpoll);
            if (__all((lane & 16) ? 1 : (v >= p))) break;
            if (++guard > (1 << 18)) { dead = 1; break; }
          }
        }
        SB();
        f16x8 ah0[8];
        {
          const f16* b0 = hb0 + (size_t)((p - 1) & 3) * H_SLOT +
                          hoff(chunk, 0, w) + lane * 8;
#pragma unroll
          for (int kt = 0; kt < 8; ++kt) ah0[kt] = ldh<F>(b0 + kt * 2048);
        }
        SB();
        // hh1 MFMAs (ah1 + LDS B) run while ah0 is in flight
        f32x4 aR = {bR1, bR1, bR1, bR1}, aZ = {bZ1, bZ1, bZ1, bZ1};
        f32x4 aI = {bI1, bI1, bI1, bI1}, aH = {bH1, bH1, bH1, bH1};
#pragma unroll
        for (int kt = 0; kt < 8; ++kt) {
          f16x8 br = *(const f16x8*)&whh1_l[(0 * 8 + kt) * 512 + lane * 8];
          f16x8 bz = *(const f16x8*)&whh1_l[(1 * 8 + kt) * 512 + lane * 8];
          f16x8 bn = *(const f16x8*)&whh1_l[(2 * 8 + kt) * 512 + lane * 8];
          aR = MFMA16(ah1[kt], br, aR);
          aZ = MFMA16(ah1[kt], bz, aZ);
          aH = MFMA16(ah1[kt], bn, aH);
        }
        SB();
        asm volatile("s_waitcnt vmcnt(0)" ::: "memory");  // ah0 done
        SB();
#pragma unroll
        for (int kt = 0; kt < 8; ++kt) {
          aR = MFMA16(ah0[kt], wfB[kt], aR);
          aZ = MFMA16(ah0[kt], wfB[8 + kt], aZ);
          aI = MFMA16(ah0[kt], wfB[16 + kt], aI);
        }
        {
          f16* d1 = hb1 + (size_t)((p - 1) & 1) * H_SLOT +
                    hoff(chunk, s_kt, w) + s_off;
#pragma unroll
          for (int i = 0; i < 4; ++i) {
            float rr = sigm(aR[i]);
            float zz = sigm(aZ[i]);
            float nn = tanh_fast(aI[i] + rr * aH[i]);
            h1r[i] = (1.f - zz) * nn + zz * h1r[i];
            sth<F>(d1 + (lgrp * 4 + i) * 8, (f16)h1r[i]);
          }
        }
        SB();
        asm volatile("s_waitcnt vmcnt(0)" ::: "memory");  // store acks
        SB();
        if (lane == 0) stf<F>(fpost1, p);
      }
    };
    if (decision == 2) loop1(TrueT{});
    else loop1(FalseT{});

    // ---- fc head partials (L1 waves own final h1) ----
    float tmp[4];
#pragma unroll
    for (int i = 0; i < 4; ++i) {
      float v = h1r[i] * fw;
#pragma unroll
      for (int m = 1; m < 16; m <<= 1) v += __shfl_xor(v, m);
      tmp[i] = v;
    }
    if (lrow == 0) {
#pragma unroll
      for (int i = 0; i < 4; ++i)
        part[(size_t)(rbase + lgrp * 4 + i) * 16 + slice] = tmp[i];
    }
  }
}

__global__ void fc_reduce(const float* __restrict__ part,
                          const float* __restrict__ fcb,
                          float* __restrict__ out) {
  int r = blockIdx.x * blockDim.x + threadIdx.x;
  if (r < B_) {
    float s = fcb[0];
#pragma unroll
    for (int i = 0; i < 16; ++i) s += part[r * 16 + i];
    out[r] = s;
  }
}

extern "C" void kernel_launch(void* const* d_in, const int* in_sizes, int n_in,
                              void* d_out, int out_size, void* d_ws, size_t ws_size,
                              hipStream_t stream) {
  const float* x    = (const float*)d_in[0];
  const float* Wih0 = (const float*)d_in[1];
  const float* Whh0 = (const float*)d_in[2];
  const float* bih0 = (const float*)d_in[3];
  const float* bhh0 = (const float*)d_in[4];
  const float* Wih1 = (const float*)d_in[5];
  const float* Whh1 = (const float*)d_in[6];
  const float* bih1 = (const float*)d_in[7];
  const float* bhh1 = (const float*)d_in[8];
  const float* fcw  = (const float*)d_in[9];
  const float* fcb  = (const float*)d_in[10];

  // ws carve-up: h0 ring-4 | h1 ring-2 | part | flags | ids | dec  (~3.2 MB)
  f16* hb0 = (f16*)d_ws;
  f16* hb1 = hb0 + (size_t)4 * H_SLOT;
  float* part = (float*)(hb1 + (size_t)2 * H_SLOT);
  int* flags = (int*)(part + 1024 * 16);
  int* ids = flags + NFLAGS;
  int* dec = ids + 256;

  init_ws<<<1024, 256, 0, stream>>>(hb0, flags);
  gru_main<<<256, 512, 0, stream>>>(x, Wih0, Whh0, Wih1, Whh1, bih0, bhh0,
                                    bih1, bhh1, fcw, hb0, hb1, part, flags,
                                    ids, dec);
  fc_reduce<<<4, 256, 0, stream>>>(part, fcb, (float*)d_out);
}